// Round 2
// baseline (2997.710 us; speedup 1.0000x reference)
//
#include <hip/hip_runtime.h>

#define N_PTS 2097152          // 2^21, fixed by the problem
#define MASK  (N_PTS - 1)

constexpr int T   = 64;        // output points per CNN block
constexpr int BLK = 256;       // threads per block

__device__ __forceinline__ float elu(float x) { return x > 0.f ? x : __expf(x) - 1.f; }

// ---------------------------------------------------------------------------
// Kernel A: CNN producing bm[i] = sigmoid(cnn(avg_diff(u)))[i] + 0.1  (f32)
// Tile of T output points; LDS ping-pong activation buffers + staged weights.
// Conv boundary = zero padding at array ends (NON-periodic), per reference.
// ---------------------------------------------------------------------------
__global__ __launch_bounds__(BLK) void cnn_kernel(
    const float* __restrict__ u,
    const float* __restrict__ w1, const float* __restrict__ b1,
    const float* __restrict__ w2, const float* __restrict__ b2,
    const float* __restrict__ w3, const float* __restrict__ b3,
    const float* __restrict__ w4, const float* __restrict__ b4,
    const float* __restrict__ w5, const float* __restrict__ b5,
    const float* __restrict__ w6, const float* __restrict__ b6,
    float* __restrict__ bm)
{
    // activation ranges (positions relative to tile start i0):
    //   dif : [i0-5, i0+T+4]  -> T+10 entries
    //   L1  : [i0-3, i0+T+2]  -> P1 = T+6, 20 ch
    //   L2/L3/L4 : [i0-1, i0+T] -> P2 = T+2, 40/80/40 ch
    //   L5  : [i0, i0+T)      -> T, 20 ch
    __shared__ float sA[40 * (T + 2)];   // 2640 f: dif, L2, L4
    __shared__ float sB[80 * (T + 2)];   // 5280 f: L1, L3, L5
    __shared__ float sW[4040];           // weights + biases (max layer: w2)

    const int tid = threadIdx.x;
    const int i0  = blockIdx.x * T;
    const int P1  = T + 6;
    const int P2  = T + 2;

    // ---- dif (avg_diff) into sA, with conv zero-pad outside [0,N) ----
    for (int t = tid; t < T + 10; t += BLK) {
        int g = i0 - 5 + t;
        float v = 0.f;
        if (g >= 0 && g < N_PTS) {
            if (g == 0)              v = u[1] - u[0];
            else if (g == N_PTS - 1) v = u[N_PTS - 1] - u[N_PTS - 2];
            else                     v = 0.5f * (u[g + 1] - u[g - 1]);
        }
        sA[t] = v;
    }
    // stage w1 (20x1x5) + b1
    for (int i = tid; i < 100; i += BLK) sW[i] = w1[i];
    for (int i = tid; i < 20;  i += BLK) sW[100 + i] = b1[i];
    __syncthreads();

    // ---- L1: 20 ch, k=5, pad=2 ----
    for (int idx = tid; idx < 20 * P1; idx += BLK) {
        int c = idx / P1, t = idx - c * P1;
        int g = i0 - 3 + t;
        float acc = sW[100 + c];
        #pragma unroll
        for (int k = 0; k < 5; ++k) acc += sW[c * 5 + k] * sA[t + k];
        acc = elu(acc);
        sB[idx] = (g >= 0 && g < N_PTS) ? acc : 0.f;
    }
    __syncthreads();
    // stage w2 (40x20x5) + b2
    for (int i = tid; i < 4000; i += BLK) sW[i] = w2[i];
    for (int i = tid; i < 40;   i += BLK) sW[4000 + i] = b2[i];
    __syncthreads();

    // ---- L2: 40 ch, k=5, pad=2 ----
    for (int idx = tid; idx < 40 * P2; idx += BLK) {
        int c = idx / P2, t = idx - c * P2;
        int g = i0 - 1 + t;
        float acc = sW[4000 + c];
        const float* wr = &sW[c * 100];
        for (int ci = 0; ci < 20; ++ci) {
            const float* in = &sB[ci * P1 + t];
            #pragma unroll
            for (int k = 0; k < 5; ++k) acc += wr[ci * 5 + k] * in[k];
        }
        acc = elu(acc);
        sA[c * P2 + t] = (g >= 0 && g < N_PTS) ? acc : 0.f;
    }
    __syncthreads();
    // stage w3 (80x40x1) + b3
    for (int i = tid; i < 3200; i += BLK) sW[i] = w3[i];
    for (int i = tid; i < 80;   i += BLK) sW[3200 + i] = b3[i];
    __syncthreads();

    // ---- L3: 80 ch, k=1 ----
    for (int idx = tid; idx < 80 * P2; idx += BLK) {
        int c = idx / P2, t = idx - c * P2;
        int g = i0 - 1 + t;
        float acc = sW[3200 + c];
        const float* wr = &sW[c * 40];
        for (int ci = 0; ci < 40; ++ci) acc += wr[ci] * sA[ci * P2 + t];
        acc = elu(acc);
        sB[c * P2 + t] = (g >= 0 && g < N_PTS) ? acc : 0.f;
    }
    __syncthreads();
    // stage w4 (40x80x1) + b4
    for (int i = tid; i < 3200; i += BLK) sW[i] = w4[i];
    for (int i = tid; i < 40;   i += BLK) sW[3200 + i] = b4[i];
    __syncthreads();

    // ---- L4: 40 ch, k=1 ----
    for (int idx = tid; idx < 40 * P2; idx += BLK) {
        int c = idx / P2, t = idx - c * P2;
        int g = i0 - 1 + t;
        float acc = sW[3200 + c];
        const float* wr = &sW[c * 80];
        for (int ci = 0; ci < 80; ++ci) acc += wr[ci] * sB[ci * P2 + t];
        acc = elu(acc);
        sA[c * P2 + t] = (g >= 0 && g < N_PTS) ? acc : 0.f;
    }
    __syncthreads();
    // stage w5 (20x40x3) + b5
    for (int i = tid; i < 2400; i += BLK) sW[i] = w5[i];
    for (int i = tid; i < 20;   i += BLK) sW[2400 + i] = b5[i];
    __syncthreads();

    // ---- L5: 20 ch, k=3, pad=1 (all outputs in-range: N % T == 0) ----
    for (int idx = tid; idx < 20 * T; idx += BLK) {
        int c = idx / T, t = idx - c * T;
        float acc = sW[2400 + c];
        const float* wr = &sW[c * 120];
        for (int ci = 0; ci < 40; ++ci) {
            const float* in = &sA[ci * P2 + t];
            #pragma unroll
            for (int k = 0; k < 3; ++k) acc += wr[ci * 3 + k] * in[k];
        }
        sB[c * T + t] = elu(acc);
    }
    __syncthreads();
    // stage w6 (1x20x1) + b6
    for (int i = tid; i < 20; i += BLK) sW[i] = w6[i];
    if (tid == 0) sW[20] = b6[0];
    __syncthreads();

    // ---- L6: 1 ch, k=1, sigmoid, +0.1 ----
    if (tid < T) {
        float acc = sW[20];
        #pragma unroll
        for (int ci = 0; ci < 20; ++ci) acc += sW[ci] * sB[ci * T + tid];
        bm[i0 + tid] = 1.f / (1.f + __expf(-acc)) + 0.1f;
    }
}

// ---------------------------------------------------------------------------
// Kernel B: WENO5 flux with bm-scaled betas; all accesses PERIODIC (jnp.roll)
// ---------------------------------------------------------------------------
__global__ __launch_bounds__(256) void weno_kernel(
    const float* __restrict__ u,
    const float* __restrict__ bm,
    float* __restrict__ out)
{
    const int i = blockIdx.x * 256 + threadIdx.x;

    const float um2 = u[(i - 2) & MASK];
    const float um1 = u[(i - 1) & MASK];
    const float u0  = u[i];
    const float up1 = u[(i + 1) & MASK];
    const float up2 = u[(i + 2) & MASK];
    const float up3 = u[(i + 3) & MASK];
    const float bmm = bm[(i - 1) & MASK];   // roll(bm, +1)[i]
    const float bm0 = bm[i];
    const float bmp = bm[(i + 1) & MASK];   // roll(bm, -1)[i]

    const float c1312 = 13.f / 12.f;
    const float s6 = 1.f / 6.f;

    // fluxes on u_right (shift -1): u->up1, um->u0, umm->um1, up->up2, upp->up3
    const float f0p = (11.f * up1 - 7.f * up2 + 2.f * up3) * s6;
    const float f1p = (2.f * u0 + 5.f * up1 - up2) * s6;
    const float f2p = (-um1 + 5.f * u0 + 2.f * up1) * s6;
    // fluxes on uu
    const float f0n = (11.f * u0 - 7.f * up1 + 2.f * up2) * s6;
    const float f1n = (2.f * um1 + 5.f * u0 - up1) * s6;
    const float f2n = (-um2 + 5.f * um1 + 2.f * u0) * s6;

    float t0, t1;
    // betas on u_right
    t0 = up1 - 2.f * up2 + up3;  t1 = 3.f * up1 - 4.f * up2 + up3;
    float bp0 = c1312 * t0 * t0 + 0.25f * t1 * t1;
    t0 = u0 - 2.f * up1 + up2;   t1 = u0 - up2;
    float bp1 = c1312 * t0 * t0 + 0.25f * t1 * t1;
    t0 = um1 - 2.f * u0 + up1;   t1 = um1 - 4.f * u0 + 3.f * up1;
    float bp2 = c1312 * t0 * t0 + 0.25f * t1 * t1;
    // betas on uu
    t0 = u0 - 2.f * up1 + up2;   t1 = 3.f * u0 - 4.f * up1 + up2;
    float bn0 = c1312 * t0 * t0 + 0.25f * t1 * t1;
    t0 = um1 - 2.f * u0 + up1;   t1 = um1 - up1;
    float bn1 = c1312 * t0 * t0 + 0.25f * t1 * t1;
    t0 = um2 - 2.f * um1 + u0;   t1 = um2 - 4.f * um1 + 3.f * u0;
    float bn2 = c1312 * t0 * t0 + 0.25f * t1 * t1;

    // scale betas: b[k] *= roll(bm, k-1)[i]  (k=0 -> bm[i+1], k=1 -> bm[i], k=2 -> bm[i-1])
    bp0 *= bmp; bp1 *= bm0; bp2 *= bmm;
    bn0 *= bmp; bn1 *= bm0; bn2 *= bmm;

    const float E = 1e-13f;
    float brs, e0, e1, e2, o0, o1, o2, s;

    // omegas (positive)
    brs = bp2 - bp0; brs *= brs;
    e0 = E + bp0; e0 *= e0;
    e1 = E + bp1; e1 *= e1;
    e2 = E + bp2; e2 *= e2;
    o0 = 0.1f * (brs + e0) / e0;
    o1 = 0.6f * (brs + e1) / e1;
    o2 = 0.3f * (brs + e2) / e2;
    s = o0 + o1 + o2;
    const float fluxp = (o0 * f0p + o1 * f1p + o2 * f2p) / s;

    // omegas (negative)
    brs = bn2 - bn0; brs *= brs;
    e0 = E + bn0; e0 *= e0;
    e1 = E + bn1; e1 *= e1;
    e2 = E + bn2; e2 *= e2;
    o0 = 0.1f * (brs + e0) / e0;
    o1 = 0.6f * (brs + e1) / e1;
    o2 = 0.3f * (brs + e2) / e2;
    s = o0 + o1 + o2;
    const float fluxn = (o0 * f0n + o1 * f1n + o2 * f2n) / s;

    out[i] = fluxp - fluxn;
}

extern "C" void kernel_launch(void* const* d_in, const int* in_sizes, int n_in,
                              void* d_out, int out_size, void* d_ws, size_t ws_size,
                              hipStream_t stream) {
    const float* u  = (const float*)d_in[0];
    const float* w1 = (const float*)d_in[1];
    const float* b1 = (const float*)d_in[2];
    const float* w2 = (const float*)d_in[3];
    const float* b2 = (const float*)d_in[4];
    const float* w3 = (const float*)d_in[5];
    const float* b3 = (const float*)d_in[6];
    const float* w4 = (const float*)d_in[7];
    const float* b4 = (const float*)d_in[8];
    const float* w5 = (const float*)d_in[9];
    const float* b5 = (const float*)d_in[10];
    const float* w6 = (const float*)d_in[11];
    const float* b6 = (const float*)d_in[12];

    float* bm = (float*)d_ws;   // N_PTS * 4 bytes of scratch

    cnn_kernel<<<N_PTS / T, BLK, 0, stream>>>(u, w1, b1, w2, b2, w3, b3,
                                              w4, b4, w5, b5, w6, b6, bm);
    weno_kernel<<<N_PTS / 256, 256, 0, stream>>>(u, bm, (float*)d_out);
}

// Round 3
// 1007.289 us; speedup vs baseline: 2.9760x; 2.9760x over previous
//
#include <hip/hip_runtime.h>
#include <cstdint>

#define N_PTS 2097152          // 2^21
#define MASK  (N_PTS - 1)

constexpr int NPOS = 128;      // grid positions per block (8 halo left, 8 right)
constexpr int POUT = 112;      // final outputs per block
constexpr int GOFF = 8;        // output starts at grid pos 8
constexpr int BLK  = 256;      // 4 waves
constexpr int NBLK = (N_PTS + POUT - 1) / POUT;   // 18725

// LDS row strides (u16 units), padded so row stride = odd multiple of 16B
constexpr int S2 = 136;        // imcol2: K=100 -> pad 128, +8
constexpr int S3 = 72;         // actT3:  K=40  -> pad 64,  +8
constexpr int S4 = 104;        // actT4:  K=80  -> pad 96,  +8
constexpr int S5 = 136;        // imcol5: K=120 -> pad 128, +8

constexpr int XOFF = 0;
constexpr int XSZ  = NPOS * S2 * 2;        // 34816 B (imcol2 / actT4 / act6)
constexpr int YOFF = XSZ;                  // 34816 B (actT3 / imcol5)
constexpr int DIFOFF = 2 * XSZ;            // 69632
constexpr int SMEM_BYTES = DIFOFF + (132 + 100 + 20) * 4;  // 70640

typedef __bf16 bf16x8 __attribute__((ext_vector_type(8)));
typedef unsigned short u16x8 __attribute__((ext_vector_type(8)));
typedef unsigned short u16x4 __attribute__((ext_vector_type(4)));
typedef float f32x4 __attribute__((ext_vector_type(4)));

__device__ __forceinline__ float elu(float x) { return x > 0.f ? x : __expf(x) - 1.f; }

// f32 -> bf16 round-to-nearest-even (inputs are finite by construction)
__device__ __forceinline__ unsigned short f2b(float f) {
    union { float f; unsigned int u; } x; x.f = f;
    unsigned int r = (x.u + 0x7fffu + ((x.u >> 16) & 1u)) >> 16;
    return (unsigned short)r;
}

// ---------------------------------------------------------------------------
// Generic MFMA layer: out[M, pos] = W[M,K] @ B[K, pos] over NPOS=128 columns.
// A (weights) from global, zero-padded in m and k (guards stale LDS pad data).
// B fragments from LDS, pos-major layout, one ds_read_b128 per fragment.
// Each wave handles 2 N-tiles; epilogue gets (mtile, pos, acc).
// ---------------------------------------------------------------------------
template<int M, int MT, int K, int KS, typename Epi>
__device__ __forceinline__ void gemm_layer(const float* __restrict__ W,
                                           const unsigned short* __restrict__ Bbuf,
                                           int SB, Epi epi)
{
    const int lane = threadIdx.x & 63;
    const int wv   = threadIdx.x >> 6;
    const int n15  = lane & 15;
    const int quad = lane >> 4;

    bf16x8 A[MT][KS];
    #pragma unroll
    for (int mt = 0; mt < MT; ++mt) {
        const int m = mt * 16 + n15;
        #pragma unroll
        for (int ks = 0; ks < KS; ++ks) {
            const int kb = ks * 32 + quad * 8;
            u16x8 t;
            #pragma unroll
            for (int j = 0; j < 8; ++j) {
                const int k = kb + j;
                const float v = (m < M && k < K) ? W[m * K + k] : 0.f;
                t[j] = f2b(v);
            }
            A[mt][ks] = __builtin_bit_cast(bf16x8, t);
        }
    }

    #pragma unroll
    for (int nt = 0; nt < 2; ++nt) {
        const int pos = (wv * 2 + nt) * 16 + n15;
        bf16x8 B[KS];
        #pragma unroll
        for (int ks = 0; ks < KS; ++ks) {
            const u16x8* p = (const u16x8*)(Bbuf + pos * SB + ks * 32 + quad * 8);
            B[ks] = __builtin_bit_cast(bf16x8, *p);
        }
        #pragma unroll
        for (int mt = 0; mt < MT; ++mt) {
            f32x4 acc = {0.f, 0.f, 0.f, 0.f};
            #pragma unroll
            for (int ks = 0; ks < KS; ++ks)
                acc = __builtin_amdgcn_mfma_f32_16x16x32_bf16(A[mt][ks], B[ks], acc, 0, 0, 0);
            epi(mt, pos, acc);
        }
    }
}

// ---------------------------------------------------------------------------
// CNN: bm = sigmoid(cnn(avg_diff(u))) + 0.1, MFMA formulation of layers 2-5
// ---------------------------------------------------------------------------
__global__ __launch_bounds__(BLK) void cnn_mfma_kernel(
    const float* __restrict__ u,
    const float* __restrict__ w1, const float* __restrict__ b1,
    const float* __restrict__ w2, const float* __restrict__ b2,
    const float* __restrict__ w3, const float* __restrict__ b3,
    const float* __restrict__ w4, const float* __restrict__ b4,
    const float* __restrict__ w5, const float* __restrict__ b5,
    const float* __restrict__ w6, const float* __restrict__ b6,
    float* __restrict__ bm)
{
    extern __shared__ char smem[];
    unsigned short* X16 = (unsigned short*)(smem + XOFF);  // imcol2 / actT4 / act6(f32)
    unsigned short* Y16 = (unsigned short*)(smem + YOFF);  // actT3 / imcol5
    float* sdif = (float*)(smem + DIFOFF);                  // 132
    float* sw1  = sdif + 132;                               // 100
    float* sb1  = sw1 + 100;                                // 20
    float* act6 = (float*)(smem + XOFF);                    // [128][20] f32

    const int tid  = threadIdx.x;
    const int lane = tid & 63;
    const int quad = lane >> 4;
    const int i0   = blockIdx.x * POUT;

    // ---- phase 1: zero X+Y (NaN safety), fill dif + w1/b1 ----
    for (int i = tid; i < (2 * XSZ) / 16; i += BLK)
        ((f32x4*)smem)[i] = f32x4{0.f, 0.f, 0.f, 0.f};
    for (int tt = tid; tt < 132; tt += BLK) {
        const int gd = i0 - 10 + tt;       // global index of this dif entry
        float v = 0.f;
        if (gd >= 0 && gd < N_PTS) {
            if (gd == 0)              v = u[1] - u[0];
            else if (gd == N_PTS - 1) v = u[N_PTS - 1] - u[N_PTS - 2];
            else                      v = 0.5f * (u[gd + 1] - u[gd - 1]);
        }
        sdif[tt] = v;
    }
    for (int i = tid; i < 100; i += BLK) sw1[i] = w1[i];
    for (int i = tid; i < 20;  i += BLK) sb1[i] = b1[i];
    __syncthreads();

    // ---- phase 2: L1 (VALU f32) + scatter into imcol2[pos][ci*5+tap] ----
    // imcol2[p][c*5+tap] = L1[c][p+tap-2]; L1 value at grid g lands at p=g+2-tap
    for (int idx = tid; idx < 20 * NPOS; idx += BLK) {
        const int c = idx >> 7, g = idx & 127;
        float a = sb1[c];
        #pragma unroll
        for (int k = 0; k < 5; ++k) a += sw1[c * 5 + k] * sdif[g + k];
        a = elu(a);
        const int gp = i0 - GOFF + g;
        if ((unsigned)gp >= (unsigned)N_PTS) a = 0.f;   // conv zero-boundary
        const unsigned short us = f2b(a);
        #pragma unroll
        for (int tap = 0; tap < 5; ++tap) {
            const int p = g + 2 - tap;
            if ((unsigned)p < (unsigned)NPOS) X16[p * S2 + c * 5 + tap] = us;
        }
    }
    __syncthreads();

    // ---- phase 3: L2  (M=40, K=100 im2col, B=X, out->actT3 in Y) ----
    gemm_layer<40, 3, 100, 4>(w2, X16, S2,
        [&](int mt, int pos, f32x4 acc) {
            const int ch0 = mt * 16 + quad * 4;
            if (ch0 >= 40) return;
            const int gp = i0 - GOFF + pos;
            const bool inr = (unsigned)gp < (unsigned)N_PTS;
            u16x4 wv;
            #pragma unroll
            for (int r = 0; r < 4; ++r) {
                float v = elu(acc[r] + b2[ch0 + r]);
                if (!inr) v = 0.f;
                wv[r] = f2b(v);
            }
            *(u16x4*)(Y16 + pos * S3 + ch0) = wv;
        });
    __syncthreads();

    // ---- phase 4: L3  (M=80, K=40, B=Y, out->actT4 in X) ----
    gemm_layer<80, 5, 40, 2>(w3, Y16, S3,
        [&](int mt, int pos, f32x4 acc) {
            const int ch0 = mt * 16 + quad * 4;
            const int gp = i0 - GOFF + pos;
            const bool inr = (unsigned)gp < (unsigned)N_PTS;
            u16x4 wv;
            #pragma unroll
            for (int r = 0; r < 4; ++r) {
                float v = elu(acc[r] + b3[ch0 + r]);
                if (!inr) v = 0.f;
                wv[r] = f2b(v);
            }
            *(u16x4*)(X16 + pos * S4 + ch0) = wv;
        });
    __syncthreads();

    // ---- phase 5: L4  (M=40, K=80, B=X, out scattered -> imcol5 in Y) ----
    // imcol5[p][ci*3+tap] = L4[ci][p+tap-1]; value at pos lands at p=pos+1-tap
    gemm_layer<40, 3, 80, 3>(w4, X16, S4,
        [&](int mt, int pos, f32x4 acc) {
            const int ch0 = mt * 16 + quad * 4;
            if (ch0 >= 40) return;
            const int gp = i0 - GOFF + pos;
            const bool inr = (unsigned)gp < (unsigned)N_PTS;
            #pragma unroll
            for (int r = 0; r < 4; ++r) {
                float v = elu(acc[r] + b4[ch0 + r]);
                if (!inr) v = 0.f;
                const unsigned short us = f2b(v);
                const int ci = ch0 + r;
                #pragma unroll
                for (int tap = 0; tap < 3; ++tap) {
                    const int p = pos + 1 - tap;
                    if ((unsigned)p < (unsigned)NPOS) Y16[p * S5 + ci * 3 + tap] = us;
                }
            }
        });
    __syncthreads();

    // ---- phase 6: L5  (M=20, K=120, B=Y, out -> act6 f32 in X) ----
    gemm_layer<20, 2, 120, 4>(w5, Y16, S5,
        [&](int mt, int pos, f32x4 acc) {
            const int ch0 = mt * 16 + quad * 4;
            if (ch0 >= 20) return;
            const int gp = i0 - GOFF + pos;
            const bool inr = (unsigned)gp < (unsigned)N_PTS;
            f32x4 wv;
            #pragma unroll
            for (int r = 0; r < 4; ++r) {
                float v = elu(acc[r] + b5[ch0 + r]);
                wv[r] = inr ? v : 0.f;
            }
            *(f32x4*)(act6 + pos * 20 + ch0) = wv;
        });
    __syncthreads();

    // ---- phase 7: L6 (20->1) + sigmoid + 0.1, store bm ----
    if (tid < POUT) {
        const int pos = tid + GOFF;
        const int gp  = i0 + tid;
        if (gp < N_PTS) {
            float a = b6[0];
            #pragma unroll
            for (int c = 0; c < 20; ++c) a += w6[c] * act6[pos * 20 + c];
            bm[gp] = 1.f / (1.f + __expf(-a)) + 0.1f;
        }
    }
}

// ---------------------------------------------------------------------------
// WENO5 flux with bm-scaled betas; periodic indexing (jnp.roll). Unchanged.
// ---------------------------------------------------------------------------
__global__ __launch_bounds__(256) void weno_kernel(
    const float* __restrict__ u,
    const float* __restrict__ bm,
    float* __restrict__ out)
{
    const int i = blockIdx.x * 256 + threadIdx.x;

    const float um2 = u[(i - 2) & MASK];
    const float um1 = u[(i - 1) & MASK];
    const float u0  = u[i];
    const float up1 = u[(i + 1) & MASK];
    const float up2 = u[(i + 2) & MASK];
    const float up3 = u[(i + 3) & MASK];
    const float bmm = bm[(i - 1) & MASK];
    const float bm0 = bm[i];
    const float bmp = bm[(i + 1) & MASK];

    const float c1312 = 13.f / 12.f;
    const float s6 = 1.f / 6.f;

    const float f0p = (11.f * up1 - 7.f * up2 + 2.f * up3) * s6;
    const float f1p = (2.f * u0 + 5.f * up1 - up2) * s6;
    const float f2p = (-um1 + 5.f * u0 + 2.f * up1) * s6;
    const float f0n = (11.f * u0 - 7.f * up1 + 2.f * up2) * s6;
    const float f1n = (2.f * um1 + 5.f * u0 - up1) * s6;
    const float f2n = (-um2 + 5.f * um1 + 2.f * u0) * s6;

    float t0, t1;
    t0 = up1 - 2.f * up2 + up3;  t1 = 3.f * up1 - 4.f * up2 + up3;
    float bp0 = c1312 * t0 * t0 + 0.25f * t1 * t1;
    t0 = u0 - 2.f * up1 + up2;   t1 = u0 - up2;
    float bp1 = c1312 * t0 * t0 + 0.25f * t1 * t1;
    t0 = um1 - 2.f * u0 + up1;   t1 = um1 - 4.f * u0 + 3.f * up1;
    float bp2 = c1312 * t0 * t0 + 0.25f * t1 * t1;
    t0 = u0 - 2.f * up1 + up2;   t1 = 3.f * u0 - 4.f * up1 + up2;
    float bn0 = c1312 * t0 * t0 + 0.25f * t1 * t1;
    t0 = um1 - 2.f * u0 + up1;   t1 = um1 - up1;
    float bn1 = c1312 * t0 * t0 + 0.25f * t1 * t1;
    t0 = um2 - 2.f * um1 + u0;   t1 = um2 - 4.f * um1 + 3.f * u0;
    float bn2 = c1312 * t0 * t0 + 0.25f * t1 * t1;

    bp0 *= bmp; bp1 *= bm0; bp2 *= bmm;
    bn0 *= bmp; bn1 *= bm0; bn2 *= bmm;

    const float E = 1e-13f;
    float brs, e0, e1, e2, o0, o1, o2, s;

    brs = bp2 - bp0; brs *= brs;
    e0 = E + bp0; e0 *= e0;
    e1 = E + bp1; e1 *= e1;
    e2 = E + bp2; e2 *= e2;
    o0 = 0.1f * (brs + e0) / e0;
    o1 = 0.6f * (brs + e1) / e1;
    o2 = 0.3f * (brs + e2) / e2;
    s = o0 + o1 + o2;
    const float fluxp = (o0 * f0p + o1 * f1p + o2 * f2p) / s;

    brs = bn2 - bn0; brs *= brs;
    e0 = E + bn0; e0 *= e0;
    e1 = E + bn1; e1 *= e1;
    e2 = E + bn2; e2 *= e2;
    o0 = 0.1f * (brs + e0) / e0;
    o1 = 0.6f * (brs + e1) / e1;
    o2 = 0.3f * (brs + e2) / e2;
    s = o0 + o1 + o2;
    const float fluxn = (o0 * f0n + o1 * f1n + o2 * f2n) / s;

    out[i] = fluxp - fluxn;
}

extern "C" void kernel_launch(void* const* d_in, const int* in_sizes, int n_in,
                              void* d_out, int out_size, void* d_ws, size_t ws_size,
                              hipStream_t stream) {
    const float* u  = (const float*)d_in[0];
    const float* w1 = (const float*)d_in[1];
    const float* b1 = (const float*)d_in[2];
    const float* w2 = (const float*)d_in[3];
    const float* b2 = (const float*)d_in[4];
    const float* w3 = (const float*)d_in[5];
    const float* b3 = (const float*)d_in[6];
    const float* w4 = (const float*)d_in[7];
    const float* b4 = (const float*)d_in[8];
    const float* w5 = (const float*)d_in[9];
    const float* b5 = (const float*)d_in[10];
    const float* w6 = (const float*)d_in[11];
    const float* b6 = (const float*)d_in[12];

    float* bm = (float*)d_ws;   // N_PTS * 4 bytes of scratch

    // >64KB static limit: request dynamic LDS (idempotent, capture-safe host call)
    (void)hipFuncSetAttribute((const void*)cnn_mfma_kernel,
                              hipFuncAttributeMaxDynamicSharedMemorySize,
                              SMEM_BYTES);

    cnn_mfma_kernel<<<NBLK, BLK, SMEM_BYTES, stream>>>(u, w1, b1, w2, b2, w3, b3,
                                                       w4, b4, w5, b5, w6, b6, bm);
    weno_kernel<<<N_PTS / 256, 256, 0, stream>>>(u, bm, (float*)d_out);
}

// Round 4
// 526.125 us; speedup vs baseline: 5.6977x; 1.9145x over previous
//
#include <hip/hip_runtime.h>
#include <cstdint>

#define N_PTS 2097152          // 2^21
#define MASK  (N_PTS - 1)

constexpr int NPOS = 128;      // grid positions per block (8 halo left, 8 right)
constexpr int POUT = 112;      // final outputs per block
constexpr int GOFF = 8;        // output starts at grid pos 8
constexpr int BLK  = 256;      // 4 waves
constexpr int NBLK = (N_PTS + POUT - 1) / POUT;   // 18725

// LDS row strides (u16 units), padded so row stride = odd multiple of 16B
constexpr int S2 = 136;        // imcol2: K=100 -> pad 128, +8
constexpr int S3 = 72;         // actT3:  K=40  -> pad 64,  +8
constexpr int S4 = 104;        // actT4:  K=80  -> pad 96,  +8
constexpr int S5 = 136;        // imcol5: K=120 -> pad 128, +8

constexpr int XOFF = 0;
constexpr int XSZ  = NPOS * S2 * 2;        // 34816 B (imcol2 / actT4 / act6)
constexpr int YOFF = XSZ;                  // 34816 B (actT3 / imcol5)
constexpr int DIFOFF = 2 * XSZ;            // 69632
// tail: sdif 132 | sw1 100 | sb1 20 | sb2 40 | sb3 80 | sb4 40 | sb5 20 | sw6 20 | sb6 1
constexpr int TAILF = 132 + 100 + 20 + 40 + 80 + 40 + 20 + 20 + 1;   // 453
constexpr int SMEM_BYTES = DIFOFF + TAILF * 4;   // 71444

// precomputed bf16 A-fragment offsets in d_ws (u16 units)
constexpr int F2 = 0;              // 3*4*64 frags = 6144 u16
constexpr int F3 = 6144;           // 5*2*64 = 5120
constexpr int F4 = 11264;          // 3*3*64 = 4608
constexpr int F5 = 15872;          // 2*4*64 = 4096 -> end 19968 u16 = 39936 B
constexpr int BM_OFF = 65536;      // bm (f32) starts at 64 KiB into d_ws

typedef __bf16 bf16x8 __attribute__((ext_vector_type(8)));
typedef unsigned short u16x8 __attribute__((ext_vector_type(8)));
typedef unsigned short u16x4 __attribute__((ext_vector_type(4)));
typedef float f32x4 __attribute__((ext_vector_type(4)));

__device__ __forceinline__ float elu(float x) { return x > 0.f ? x : __expf(x) - 1.f; }

// f32 -> bf16 round-to-nearest-even (inputs finite by construction)
__device__ __forceinline__ unsigned short f2b(float f) {
    union { float f; unsigned int u; } x; x.f = f;
    unsigned int r = (x.u + 0x7fffu + ((x.u >> 16) & 1u)) >> 16;
    return (unsigned short)r;
}

// ---------------------------------------------------------------------------
// Prep: pack W[M,K] f32 -> bf16 MFMA A-fragments in per-lane order.
// frag f = (mt*KS+ks)*64 + lane; elems j: m=mt*16+(lane&15), k=ks*32+(lane>>4)*8+j
// Zero-padded in m and k so pad columns of B contribute exactly 0.
// ---------------------------------------------------------------------------
template<int M, int MT, int K, int KS>
__device__ __forceinline__ void pack_frags(const float* __restrict__ W,
                                           unsigned short* __restrict__ dst, int tid)
{
    for (int f = tid; f < MT * KS * 64; f += BLK) {
        const int lane = f & 63;
        const int fi = f >> 6;
        const int mt = fi / KS, ks = fi - mt * KS;
        const int m  = mt * 16 + (lane & 15);
        const int kb = ks * 32 + (lane >> 4) * 8;
        u16x8 t;
        #pragma unroll
        for (int j = 0; j < 8; ++j) {
            const int k = kb + j;
            t[j] = f2b((m < M && k < K) ? W[m * K + k] : 0.f);
        }
        *(u16x8*)(dst + f * 8) = t;
    }
}

__global__ __launch_bounds__(BLK) void prep_kernel(
    const float* __restrict__ w2, const float* __restrict__ w3,
    const float* __restrict__ w4, const float* __restrict__ w5,
    unsigned short* __restrict__ frags)
{
    const int tid = threadIdx.x;
    pack_frags<40, 3, 100, 4>(w2, frags + F2, tid);
    pack_frags<80, 5,  40, 2>(w3, frags + F3, tid);
    pack_frags<40, 3,  80, 3>(w4, frags + F4, tid);
    pack_frags<20, 2, 120, 4>(w5, frags + F5, tid);
}

// ---------------------------------------------------------------------------
// Generic MFMA layer: out[M, pos] = W @ B over NPOS=128 position columns.
// A fragments: precomputed bf16, one coalesced 16B load each.
// B fragments: LDS pos-major, one ds_read_b128 each.
// ---------------------------------------------------------------------------
template<int MT, int KS, typename Epi>
__device__ __forceinline__ void gemm_layer(const unsigned short* __restrict__ Af,
                                           const unsigned short* __restrict__ Bbuf,
                                           int SB, Epi epi)
{
    const int lane = threadIdx.x & 63;
    const int wv   = threadIdx.x >> 6;
    const int n15  = lane & 15;
    const int quad = lane >> 4;

    bf16x8 A[MT][KS];
    #pragma unroll
    for (int mt = 0; mt < MT; ++mt)
        #pragma unroll
        for (int ks = 0; ks < KS; ++ks)
            A[mt][ks] = __builtin_bit_cast(bf16x8,
                *(const u16x8*)(Af + ((mt * KS + ks) * 64 + lane) * 8));

    #pragma unroll
    for (int nt = 0; nt < 2; ++nt) {
        const int pos = (wv * 2 + nt) * 16 + n15;
        bf16x8 B[KS];
        #pragma unroll
        for (int ks = 0; ks < KS; ++ks) {
            const u16x8* p = (const u16x8*)(Bbuf + pos * SB + ks * 32 + quad * 8);
            B[ks] = __builtin_bit_cast(bf16x8, *p);
        }
        #pragma unroll
        for (int mt = 0; mt < MT; ++mt) {
            f32x4 acc = {0.f, 0.f, 0.f, 0.f};
            #pragma unroll
            for (int ks = 0; ks < KS; ++ks)
                acc = __builtin_amdgcn_mfma_f32_16x16x32_bf16(A[mt][ks], B[ks], acc, 0, 0, 0);
            epi(mt, pos, acc);
        }
    }
}

// ---------------------------------------------------------------------------
// CNN: bm = sigmoid(cnn(avg_diff(u))) + 0.1, MFMA formulation of layers 2-5
// ---------------------------------------------------------------------------
__global__ __launch_bounds__(BLK) void cnn_mfma_kernel(
    const float* __restrict__ u,
    const float* __restrict__ w1, const float* __restrict__ b1,
    const float* __restrict__ b2, const float* __restrict__ b3,
    const float* __restrict__ b4, const float* __restrict__ b5,
    const float* __restrict__ w6, const float* __restrict__ b6,
    const unsigned short* __restrict__ frags,
    float* __restrict__ bm)
{
    extern __shared__ char smem[];
    unsigned short* X16 = (unsigned short*)(smem + XOFF);  // imcol2 / actT4 / act6(f32)
    unsigned short* Y16 = (unsigned short*)(smem + YOFF);  // actT3 / imcol5
    float* sdif = (float*)(smem + DIFOFF);                  // 132
    float* sw1  = sdif + 132;                               // 100
    float* sb1  = sw1 + 100;                                // 20
    float* sb2  = sb1 + 20;                                 // 40
    float* sb3  = sb2 + 40;                                 // 80
    float* sb4  = sb3 + 80;                                 // 40
    float* sb5  = sb4 + 40;                                 // 20
    float* sw6  = sb5 + 20;                                 // 20
    float* sb6  = sw6 + 20;                                 // 1
    float* act6 = (float*)(smem + XOFF);                    // [128][20] f32

    const int tid  = threadIdx.x;
    const int lane = tid & 63;
    const int quad = lane >> 4;
    const int i0   = blockIdx.x * POUT;

    // ---- phase 1: zero X+Y (stale-NaN safety for pad columns), fill dif + params ----
    for (int i = tid; i < (2 * XSZ) / 16; i += BLK)
        ((f32x4*)smem)[i] = f32x4{0.f, 0.f, 0.f, 0.f};
    for (int tt = tid; tt < 132; tt += BLK) {
        const int gd = i0 - 10 + tt;
        float v = 0.f;
        if (gd >= 0 && gd < N_PTS) {
            if (gd == 0)              v = u[1] - u[0];
            else if (gd == N_PTS - 1) v = u[N_PTS - 1] - u[N_PTS - 2];
            else                      v = 0.5f * (u[gd + 1] - u[gd - 1]);
        }
        sdif[tt] = v;
    }
    for (int i = tid; i < 100; i += BLK) sw1[i] = w1[i];
    if (tid < 20)  sb1[tid] = b1[tid];
    else if (tid < 60)  sb2[tid - 20]  = b2[tid - 20];
    else if (tid < 140) sb3[tid - 60]  = b3[tid - 60];
    else if (tid < 180) sb4[tid - 140] = b4[tid - 140];
    else if (tid < 200) sb5[tid - 180] = b5[tid - 180];
    else if (tid < 220) sw6[tid - 200] = w6[tid - 200];
    else if (tid == 220) sb6[0] = b6[0];
    __syncthreads();

    // ---- phase 2: L1 (VALU f32) + scatter into imcol2[pos][ci*5+tap] ----
    for (int idx = tid; idx < 20 * NPOS; idx += BLK) {
        const int c = idx >> 7, g = idx & 127;
        float a = sb1[c];
        #pragma unroll
        for (int k = 0; k < 5; ++k) a += sw1[c * 5 + k] * sdif[g + k];
        a = elu(a);
        const int gp = i0 - GOFF + g;
        if ((unsigned)gp >= (unsigned)N_PTS) a = 0.f;   // conv zero-boundary
        const unsigned short us = f2b(a);
        #pragma unroll
        for (int tap = 0; tap < 5; ++tap) {
            const int p = g + 2 - tap;
            if ((unsigned)p < (unsigned)NPOS) X16[p * S2 + c * 5 + tap] = us;
        }
    }
    __syncthreads();

    // ---- phase 3: L2  (M=40, K=100 im2col, B=X, out->actT3 in Y) ----
    gemm_layer<3, 4>(frags + F2, X16, S2,
        [&](int mt, int pos, f32x4 acc) {
            const int ch0 = mt * 16 + quad * 4;
            if (ch0 >= 40) return;
            const int gp = i0 - GOFF + pos;
            const bool inr = (unsigned)gp < (unsigned)N_PTS;
            u16x4 wv;
            #pragma unroll
            for (int r = 0; r < 4; ++r) {
                float v = elu(acc[r] + sb2[ch0 + r]);
                if (!inr) v = 0.f;
                wv[r] = f2b(v);
            }
            *(u16x4*)(Y16 + pos * S3 + ch0) = wv;
        });
    __syncthreads();

    // ---- phase 4: L3  (M=80, K=40, B=Y, out->actT4 in X) ----
    gemm_layer<5, 2>(frags + F3, Y16, S3,
        [&](int mt, int pos, f32x4 acc) {
            const int ch0 = mt * 16 + quad * 4;
            const int gp = i0 - GOFF + pos;
            const bool inr = (unsigned)gp < (unsigned)N_PTS;
            u16x4 wv;
            #pragma unroll
            for (int r = 0; r < 4; ++r) {
                float v = elu(acc[r] + sb3[ch0 + r]);
                if (!inr) v = 0.f;
                wv[r] = f2b(v);
            }
            *(u16x4*)(X16 + pos * S4 + ch0) = wv;
        });
    __syncthreads();

    // ---- phase 5: L4  (M=40, K=80, B=X, out scattered -> imcol5 in Y) ----
    gemm_layer<3, 3>(frags + F4, X16, S4,
        [&](int mt, int pos, f32x4 acc) {
            const int ch0 = mt * 16 + quad * 4;
            if (ch0 >= 40) return;
            const int gp = i0 - GOFF + pos;
            const bool inr = (unsigned)gp < (unsigned)N_PTS;
            #pragma unroll
            for (int r = 0; r < 4; ++r) {
                float v = elu(acc[r] + sb4[ch0 + r]);
                if (!inr) v = 0.f;
                const unsigned short us = f2b(v);
                const int ci = ch0 + r;
                #pragma unroll
                for (int tap = 0; tap < 3; ++tap) {
                    const int p = pos + 1 - tap;
                    if ((unsigned)p < (unsigned)NPOS) Y16[p * S5 + ci * 3 + tap] = us;
                }
            }
        });
    __syncthreads();

    // ---- phase 6: L5  (M=20, K=120, B=Y, out -> act6 f32 in X) ----
    gemm_layer<2, 4>(frags + F5, Y16, S5,
        [&](int mt, int pos, f32x4 acc) {
            const int ch0 = mt * 16 + quad * 4;
            if (ch0 >= 20) return;
            const int gp = i0 - GOFF + pos;
            const bool inr = (unsigned)gp < (unsigned)N_PTS;
            f32x4 wv;
            #pragma unroll
            for (int r = 0; r < 4; ++r) {
                float v = elu(acc[r] + sb5[ch0 + r]);
                wv[r] = inr ? v : 0.f;
            }
            *(f32x4*)(act6 + pos * 20 + ch0) = wv;
        });
    __syncthreads();

    // ---- phase 7: L6 (20->1) + sigmoid + 0.1, store bm ----
    if (tid < POUT) {
        const int pos = tid + GOFF;
        const int gp  = i0 + tid;
        if (gp < N_PTS) {
            float a = sb6[0];
            #pragma unroll
            for (int c = 0; c < 20; ++c) a += sw6[c] * act6[pos * 20 + c];
            bm[gp] = 1.f / (1.f + __expf(-a)) + 0.1f;
        }
    }
}

// ---------------------------------------------------------------------------
// WENO5 flux with bm-scaled betas; periodic indexing (jnp.roll). Unchanged.
// ---------------------------------------------------------------------------
__global__ __launch_bounds__(256) void weno_kernel(
    const float* __restrict__ u,
    const float* __restrict__ bm,
    float* __restrict__ out)
{
    const int i = blockIdx.x * 256 + threadIdx.x;

    const float um2 = u[(i - 2) & MASK];
    const float um1 = u[(i - 1) & MASK];
    const float u0  = u[i];
    const float up1 = u[(i + 1) & MASK];
    const float up2 = u[(i + 2) & MASK];
    const float up3 = u[(i + 3) & MASK];
    const float bmm = bm[(i - 1) & MASK];
    const float bm0 = bm[i];
    const float bmp = bm[(i + 1) & MASK];

    const float c1312 = 13.f / 12.f;
    const float s6 = 1.f / 6.f;

    const float f0p = (11.f * up1 - 7.f * up2 + 2.f * up3) * s6;
    const float f1p = (2.f * u0 + 5.f * up1 - up2) * s6;
    const float f2p = (-um1 + 5.f * u0 + 2.f * up1) * s6;
    const float f0n = (11.f * u0 - 7.f * up1 + 2.f * up2) * s6;
    const float f1n = (2.f * um1 + 5.f * u0 - up1) * s6;
    const float f2n = (-um2 + 5.f * um1 + 2.f * u0) * s6;

    float t0, t1;
    t0 = up1 - 2.f * up2 + up3;  t1 = 3.f * up1 - 4.f * up2 + up3;
    float bp0 = c1312 * t0 * t0 + 0.25f * t1 * t1;
    t0 = u0 - 2.f * up1 + up2;   t1 = u0 - up2;
    float bp1 = c1312 * t0 * t0 + 0.25f * t1 * t1;
    t0 = um1 - 2.f * u0 + up1;   t1 = um1 - 4.f * u0 + 3.f * up1;
    float bp2 = c1312 * t0 * t0 + 0.25f * t1 * t1;
    t0 = u0 - 2.f * up1 + up2;   t1 = 3.f * u0 - 4.f * up1 + up2;
    float bn0 = c1312 * t0 * t0 + 0.25f * t1 * t1;
    t0 = um1 - 2.f * u0 + up1;   t1 = um1 - up1;
    float bn1 = c1312 * t0 * t0 + 0.25f * t1 * t1;
    t0 = um2 - 2.f * um1 + u0;   t1 = um2 - 4.f * um1 + 3.f * u0;
    float bn2 = c1312 * t0 * t0 + 0.25f * t1 * t1;

    bp0 *= bmp; bp1 *= bm0; bp2 *= bmm;
    bn0 *= bmp; bn1 *= bm0; bn2 *= bmm;

    const float E = 1e-13f;
    float brs, e0, e1, e2, o0, o1, o2, s;

    brs = bp2 - bp0; brs *= brs;
    e0 = E + bp0; e0 *= e0;
    e1 = E + bp1; e1 *= e1;
    e2 = E + bp2; e2 *= e2;
    o0 = 0.1f * (brs + e0) / e0;
    o1 = 0.6f * (brs + e1) / e1;
    o2 = 0.3f * (brs + e2) / e2;
    s = o0 + o1 + o2;
    const float fluxp = (o0 * f0p + o1 * f1p + o2 * f2p) / s;

    brs = bn2 - bn0; brs *= brs;
    e0 = E + bn0; e0 *= e0;
    e1 = E + bn1; e1 *= e1;
    e2 = E + bn2; e2 *= e2;
    o0 = 0.1f * (brs + e0) / e0;
    o1 = 0.6f * (brs + e1) / e1;
    o2 = 0.3f * (brs + e2) / e2;
    s = o0 + o1 + o2;
    const float fluxn = (o0 * f0n + o1 * f1n + o2 * f2n) / s;

    out[i] = fluxp - fluxn;
}

extern "C" void kernel_launch(void* const* d_in, const int* in_sizes, int n_in,
                              void* d_out, int out_size, void* d_ws, size_t ws_size,
                              hipStream_t stream) {
    const float* u  = (const float*)d_in[0];
    const float* w1 = (const float*)d_in[1];
    const float* b1 = (const float*)d_in[2];
    const float* w2 = (const float*)d_in[3];
    const float* b2 = (const float*)d_in[4];
    const float* w3 = (const float*)d_in[5];
    const float* b3 = (const float*)d_in[6];
    const float* w4 = (const float*)d_in[7];
    const float* b4 = (const float*)d_in[8];
    const float* w5 = (const float*)d_in[9];
    const float* b5 = (const float*)d_in[10];
    const float* w6 = (const float*)d_in[11];
    const float* b6 = (const float*)d_in[12];

    unsigned short* frags = (unsigned short*)d_ws;                 // 39936 B
    float* bm = (float*)((char*)d_ws + BM_OFF);                    // 8 MB

    (void)hipFuncSetAttribute((const void*)cnn_mfma_kernel,
                              hipFuncAttributeMaxDynamicSharedMemorySize,
                              SMEM_BYTES);

    prep_kernel<<<1, BLK, 0, stream>>>(w2, w3, w4, w5, frags);
    cnn_mfma_kernel<<<NBLK, BLK, SMEM_BYTES, stream>>>(u, w1, b1, b2, b3, b4, b5,
                                                       w6, b6, frags, bm);
    weno_kernel<<<N_PTS / 256, 256, 0, stream>>>(u, bm, (float*)d_out);
}

// Round 5
// 369.090 us; speedup vs baseline: 8.1219x; 1.4255x over previous
//
#include <hip/hip_runtime.h>
#include <cstdint>

#define N_PTS 2097152          // 2^21
#define MASK  (N_PTS - 1)

constexpr int NPOS = 128;      // grid positions per block (pos q in [0,128))
constexpr int POUT = 112;      // outputs per block: g = i0 + tid, tid < 112, q = tid+8
constexpr int BLK  = 256;      // 4 waves
constexpr int NBLK = (N_PTS + POUT - 1) / POUT;   // 18725

// LDS activation strides (u16 units); row stride = odd multiple of 16 B
constexpr int ST1 = 40;    // act1: 20 ch, k-pad to 32 (KS=1), 132 rows (q offset +2)
constexpr int ST2 = 72;    // act2: 40 ch, k-pad to 64 (KS=2), 128 rows
constexpr int ST3 = 104;   // act3: 80 ch, k-pad to 96 (KS=3), 128 rows
constexpr int ST4 = 72;    // act4: 40 ch, k-pad to 64 (KS=2), 130 rows (q offset +1)
constexpr int ST6 = 130;   // act6T: [20 ch][130 pos] f32 (transposed, conflict-free)

constexpr int SLOTA_OFF = 0;
constexpr int SLOTA_SZ  = 128 * ST3 * 2;            // 26624 B (act1 / act3 / act6T)
constexpr int SLOTB_OFF = SLOTA_SZ;
constexpr int SLOTB_SZ  = 130 * ST4 * 2;            // 18720 B (act2 / act4)
constexpr int TAIL_OFF  = SLOTB_OFF + SLOTB_SZ;     // 45344
// tail f32: sdif 136 | sw1 100 | sb1 20 | sb2 40 | sb3 80 | sb4 40 | sb5 20 | sw6 20 | sb6 1 | sbm 114
constexpr int SMEM_BYTES = TAIL_OFF + 571 * 4 + 4;  // 47632

// precomputed bf16 A-fragments in d_ws (u16 units); frag = ((t*MT+mt)*KS+ks)
constexpr int F2 = 0;          // L2: 5 taps x MT3 x KS1 = 15 frags x 512 u16
constexpr int F3 = 7680;       // L3: 1 x 5 x 2 = 10 frags
constexpr int F4 = 12800;      // L4: 1 x 3 x 3 = 9
constexpr int F5 = 17408;      // L5: 3 x 2 x 2 = 12  -> ends 23552 u16 = 47104 B
constexpr int BME_OFF = 49152; // 4 edge bm values (f32): bm[0], bm[1], bm[N-2], bm[N-1]

typedef __bf16 bf16x8 __attribute__((ext_vector_type(8)));
typedef unsigned short u16x8 __attribute__((ext_vector_type(8)));
typedef unsigned short u16x4 __attribute__((ext_vector_type(4)));
typedef float f32x4 __attribute__((ext_vector_type(4)));

__device__ __forceinline__ float elu(float x) { return x > 0.f ? x : __expf(x) - 1.f; }

__device__ __forceinline__ unsigned short f2b(float f) {
    union { float f; unsigned int u; } x; x.f = f;
    unsigned int r = (x.u + 0x7fffu + ((x.u >> 16) & 1u)) >> 16;
    return (unsigned short)r;
}

// ---------------------------------------------------------------------------
// Prep: per-tap weight matrices W[M, CI, KT] -> bf16 MFMA A-fragments,
// lane-ordered, zero-padded in m and k (so B pad rows only meet zero weights).
// ---------------------------------------------------------------------------
template<int M, int MT, int CI, int KS, int KT>
__device__ __forceinline__ void pack_tap(const float* __restrict__ W,
                                         unsigned short* __restrict__ dst, int tid)
{
    for (int f = tid; f < KT * MT * KS * 64; f += BLK) {
        const int lane = f & 63;
        int fi = f >> 6;
        const int ks = fi % KS; fi /= KS;
        const int mt = fi % MT; fi /= MT;
        const int t  = fi;
        const int m  = mt * 16 + (lane & 15);
        const int kb = ks * 32 + (lane >> 4) * 8;
        u16x8 v;
        #pragma unroll
        for (int j = 0; j < 8; ++j) {
            const int k = kb + j;
            v[j] = f2b((m < M && k < CI) ? W[(m * CI + k) * KT + t] : 0.f);
        }
        *(u16x8*)(dst + f * 8) = v;
    }
}

__global__ __launch_bounds__(BLK) void prep_kernel(
    const float* __restrict__ w2, const float* __restrict__ w3,
    const float* __restrict__ w4, const float* __restrict__ w5,
    unsigned short* __restrict__ frags)
{
    const int tid = threadIdx.x;
    pack_tap<40, 3, 20, 1, 5>(w2, frags + F2, tid);
    pack_tap<80, 5, 40, 2, 1>(w3, frags + F3, tid);
    pack_tap<40, 3, 80, 3, 1>(w4, frags + F4, tid);
    pack_tap<20, 2, 40, 2, 3>(w5, frags + F5, tid);
}

// ---------------------------------------------------------------------------
// Tap-decomposed MFMA layer: out[m, q] = sum_t W_t @ act[:, row q+t].
// B physical row = pos + t (buffers stored with matching row offsets).
// ---------------------------------------------------------------------------
template<int TAPS, int MT, int KS, typename Epi>
__device__ __forceinline__ void gemm_tap(const unsigned short* __restrict__ Af,
                                         const unsigned short* __restrict__ Bbuf,
                                         int SB, Epi epi)
{
    const int lane = threadIdx.x & 63;
    const int wv   = threadIdx.x >> 6;
    const int n15  = lane & 15;
    const int quad = lane >> 4;

    #pragma unroll
    for (int nt = 0; nt < 2; ++nt) {
        const int pos = (wv * 2 + nt) * 16 + n15;
        bf16x8 B[TAPS][KS];
        #pragma unroll
        for (int t = 0; t < TAPS; ++t)
            #pragma unroll
            for (int ks = 0; ks < KS; ++ks)
                B[t][ks] = __builtin_bit_cast(bf16x8,
                    *(const u16x8*)(Bbuf + (pos + t) * SB + ks * 32 + quad * 8));
        #pragma unroll
        for (int mt = 0; mt < MT; ++mt) {
            f32x4 acc = {0.f, 0.f, 0.f, 0.f};
            #pragma unroll
            for (int t = 0; t < TAPS; ++t)
                #pragma unroll
                for (int ks = 0; ks < KS; ++ks)
                    acc = __builtin_amdgcn_mfma_f32_16x16x32_bf16(
                        __builtin_bit_cast(bf16x8,
                            *(const u16x8*)(Af + (((t * MT + mt) * KS + ks) * 64 + lane) * 8)),
                        B[t][ks], acc, 0, 0, 0);
            epi(mt, pos, acc);
        }
    }
}

// ---------------------------------------------------------------------------
// WENO5 flux at point i (periodic u indexing), given bm[i-1], bm[i], bm[i+1]
// ---------------------------------------------------------------------------
__device__ __forceinline__ float weno_point(const float* __restrict__ u, int i,
                                            float bmm, float bm0, float bmp)
{
    const float um2 = u[(i - 2) & MASK];
    const float um1 = u[(i - 1) & MASK];
    const float u0  = u[i];
    const float up1 = u[(i + 1) & MASK];
    const float up2 = u[(i + 2) & MASK];
    const float up3 = u[(i + 3) & MASK];

    const float c1312 = 13.f / 12.f;
    const float s6 = 1.f / 6.f;

    const float f0p = (11.f * up1 - 7.f * up2 + 2.f * up3) * s6;
    const float f1p = (2.f * u0 + 5.f * up1 - up2) * s6;
    const float f2p = (-um1 + 5.f * u0 + 2.f * up1) * s6;
    const float f0n = (11.f * u0 - 7.f * up1 + 2.f * up2) * s6;
    const float f1n = (2.f * um1 + 5.f * u0 - up1) * s6;
    const float f2n = (-um2 + 5.f * um1 + 2.f * u0) * s6;

    float t0, t1;
    t0 = up1 - 2.f * up2 + up3;  t1 = 3.f * up1 - 4.f * up2 + up3;
    float bp0 = c1312 * t0 * t0 + 0.25f * t1 * t1;
    t0 = u0 - 2.f * up1 + up2;   t1 = u0 - up2;
    float bp1 = c1312 * t0 * t0 + 0.25f * t1 * t1;
    t0 = um1 - 2.f * u0 + up1;   t1 = um1 - 4.f * u0 + 3.f * up1;
    float bp2 = c1312 * t0 * t0 + 0.25f * t1 * t1;
    t0 = u0 - 2.f * up1 + up2;   t1 = 3.f * u0 - 4.f * up1 + up2;
    float bn0 = c1312 * t0 * t0 + 0.25f * t1 * t1;
    t0 = um1 - 2.f * u0 + up1;   t1 = um1 - up1;
    float bn1 = c1312 * t0 * t0 + 0.25f * t1 * t1;
    t0 = um2 - 2.f * um1 + u0;   t1 = um2 - 4.f * um1 + 3.f * u0;
    float bn2 = c1312 * t0 * t0 + 0.25f * t1 * t1;

    bp0 *= bmp; bp1 *= bm0; bp2 *= bmm;
    bn0 *= bmp; bn1 *= bm0; bn2 *= bmm;

    const float E = 1e-13f;
    float brs, e0, e1, e2, o0, o1, o2, s;

    brs = bp2 - bp0; brs *= brs;
    e0 = E + bp0; e0 *= e0;
    e1 = E + bp1; e1 *= e1;
    e2 = E + bp2; e2 *= e2;
    o0 = 0.1f * (brs + e0) / e0;
    o1 = 0.6f * (brs + e1) / e1;
    o2 = 0.3f * (brs + e2) / e2;
    s = o0 + o1 + o2;
    const float fluxp = (o0 * f0p + o1 * f1p + o2 * f2p) / s;

    brs = bn2 - bn0; brs *= brs;
    e0 = E + bn0; e0 *= e0;
    e1 = E + bn1; e1 *= e1;
    e2 = E + bn2; e2 *= e2;
    o0 = 0.1f * (brs + e0) / e0;
    o1 = 0.6f * (brs + e1) / e1;
    o2 = 0.3f * (brs + e2) / e2;
    s = o0 + o1 + o2;
    const float fluxn = (o0 * f0n + o1 * f1n + o2 * f2n) / s;

    return fluxp - fluxn;
}

// ---------------------------------------------------------------------------
// Fused CNN + WENO. Each block: bm for q in [7,121) locally, WENO for 112 pts.
// ---------------------------------------------------------------------------
__global__ __launch_bounds__(BLK, 3) void cnn_weno_kernel(
    const float* __restrict__ u,
    const float* __restrict__ w1, const float* __restrict__ b1,
    const float* __restrict__ b2, const float* __restrict__ b3,
    const float* __restrict__ b4, const float* __restrict__ b5,
    const float* __restrict__ w6, const float* __restrict__ b6,
    const unsigned short* __restrict__ frags,
    float* __restrict__ bmE,
    float* __restrict__ out)
{
    extern __shared__ char smem[];
    unsigned short* act1 = (unsigned short*)(smem + SLOTA_OFF);  // [132][ST1]
    unsigned short* act3 = (unsigned short*)(smem + SLOTA_OFF);  // [128][ST3]
    float*          act6T = (float*)(smem + SLOTA_OFF);          // [20][ST6] f32
    unsigned short* act2 = (unsigned short*)(smem + SLOTB_OFF);  // [128][ST2]
    unsigned short* act4 = (unsigned short*)(smem + SLOTB_OFF);  // [130][ST4]
    float* sdif = (float*)(smem + TAIL_OFF);   // 136
    float* sw1  = sdif + 136;                  // 100
    float* sb1  = sw1 + 100;                   // 20
    float* sb2  = sb1 + 20;                    // 40
    float* sb3  = sb2 + 40;                    // 80
    float* sb4  = sb3 + 80;                    // 40
    float* sb5  = sb4 + 40;                    // 20
    float* sw6  = sb5 + 20;                    // 20
    float* sb6  = sw6 + 20;                    // 1
    float* sbm  = sb6 + 1;                     // 114  (sbm[j] = bm at g = i0 + j - 1)

    const int tid  = threadIdx.x;
    const int lane = tid & 63;
    const int quad = lane >> 4;
    const int i0   = blockIdx.x * POUT;

    // ---- phase 1: zero both slots (finite-guard for k-pad / row-pad), dif, params ----
    for (int i = tid; i < TAIL_OFF / 16; i += BLK)
        ((f32x4*)smem)[i] = f32x4{0.f, 0.f, 0.f, 0.f};
    for (int d = tid; d < 136; d += BLK) {
        const int g = i0 - 12 + d;             // dif logical q = d-4, g = i0-8+q
        float v = 0.f;
        if (g >= 0 && g < N_PTS) {
            if (g == 0)              v = u[1] - u[0];
            else if (g == N_PTS - 1) v = u[N_PTS - 1] - u[N_PTS - 2];
            else                     v = 0.5f * (u[g + 1] - u[g - 1]);
        }
        sdif[d] = v;
    }
    for (int i = tid; i < 100; i += BLK) sw1[i] = w1[i];
    if (tid < 20)  sb1[tid] = b1[tid];
    else if (tid < 60)  sb2[tid - 20]  = b2[tid - 20];
    else if (tid < 140) sb3[tid - 60]  = b3[tid - 60];
    else if (tid < 180) sb4[tid - 140] = b4[tid - 140];
    else if (tid < 200) sb5[tid - 180] = b5[tid - 180];
    else if (tid < 220) sw6[tid - 200] = w6[tid - 200];
    else if (tid == 220) sb6[0] = b6[0];
    __syncthreads();

    // ---- phase 2: L1 (VALU) -> act1[r][c], r = q+2 in [0,132) ----
    for (int task = tid; task < 132 * 5; task += BLK) {
        const int r  = task / 5;
        const int c0 = (task - r * 5) * 4;
        const float d0 = sdif[r], d1 = sdif[r+1], d2 = sdif[r+2],
                    d3 = sdif[r+3], d4 = sdif[r+4];
        const int g = i0 - 10 + r;             // logical q = r-2
        const bool inr = (unsigned)g < (unsigned)N_PTS;
        u16x4 ov;
        #pragma unroll
        for (int j = 0; j < 4; ++j) {
            const int c = c0 + j;
            float a = sb1[c] + sw1[c*5]*d0 + sw1[c*5+1]*d1 + sw1[c*5+2]*d2
                             + sw1[c*5+3]*d3 + sw1[c*5+4]*d4;
            a = elu(a);
            ov[j] = f2b(inr ? a : 0.f);
        }
        *(u16x4*)(act1 + r * ST1 + c0) = ov;
    }
    __syncthreads();

    // ---- phase 3: L2 (40ch, 5 taps) act1 -> act2 ----
    gemm_tap<5, 3, 1>(frags + F2, act1, ST1,
        [&](int mt, int pos, f32x4 acc) {
            const int ch0 = mt * 16 + quad * 4;
            if (ch0 >= 40) return;
            const int g = i0 - 8 + pos;
            const bool inr = (unsigned)g < (unsigned)N_PTS;
            u16x4 wv;
            #pragma unroll
            for (int r = 0; r < 4; ++r) {
                const float v = elu(acc[r] + sb2[ch0 + r]);
                wv[r] = f2b(inr ? v : 0.f);
            }
            *(u16x4*)(act2 + pos * ST2 + ch0) = wv;
        });
    __syncthreads();

    // ---- phase 4: L3 (80ch, k=1) act2 -> act3 ----
    gemm_tap<1, 5, 2>(frags + F3, act2, ST2,
        [&](int mt, int pos, f32x4 acc) {
            const int ch0 = mt * 16 + quad * 4;
            const int g = i0 - 8 + pos;
            const bool inr = (unsigned)g < (unsigned)N_PTS;
            u16x4 wv;
            #pragma unroll
            for (int r = 0; r < 4; ++r) {
                const float v = elu(acc[r] + sb3[ch0 + r]);
                wv[r] = f2b(inr ? v : 0.f);
            }
            *(u16x4*)(act3 + pos * ST3 + ch0) = wv;
        });
    __syncthreads();

    // ---- phase 5: L4 (40ch, k=1) act3 -> act4 (row offset +1) ----
    gemm_tap<1, 3, 3>(frags + F4, act3, ST3,
        [&](int mt, int pos, f32x4 acc) {
            const int ch0 = mt * 16 + quad * 4;
            if (ch0 >= 40) return;
            const int g = i0 - 8 + pos;
            const bool inr = (unsigned)g < (unsigned)N_PTS;
            u16x4 wv;
            #pragma unroll
            for (int r = 0; r < 4; ++r) {
                const float v = elu(acc[r] + sb4[ch0 + r]);
                wv[r] = f2b(inr ? v : 0.f);
            }
            *(u16x4*)(act4 + (pos + 1) * ST4 + ch0) = wv;
        });
    __syncthreads();

    // ---- phase 6: L5 (20ch, 3 taps) act4 -> act6T (transposed f32) ----
    gemm_tap<3, 2, 2>(frags + F5, act4, ST4,
        [&](int mt, int pos, f32x4 acc) {
            const int ch0 = mt * 16 + quad * 4;
            if (ch0 >= 20) return;
            const int g = i0 - 8 + pos;
            const bool inr = (unsigned)g < (unsigned)N_PTS;
            #pragma unroll
            for (int r = 0; r < 4; ++r) {
                const float v = elu(acc[r] + sb5[ch0 + r]);
                act6T[(ch0 + r) * ST6 + pos] = inr ? v : 0.f;
            }
        });
    __syncthreads();

    // ---- phase 7: L6 + sigmoid + 0.1 -> sbm; export 4 edge bm values ----
    if (tid < 114) {
        const int pos = tid + 7;
        float a = sb6[0];
        #pragma unroll
        for (int c = 0; c < 20; ++c) a += sw6[c] * act6T[c * ST6 + pos];
        const float v = 1.f / (1.f + __expf(-a)) + 0.1f;
        sbm[tid] = v;
        const int g = i0 + tid - 1;
        if (blockIdx.x == 0) {
            if (g == 0) bmE[0] = v;
            else if (g == 1) bmE[1] = v;
        }
        if (blockIdx.x == NBLK - 1) {
            if (g == N_PTS - 2) bmE[2] = v;
            else if (g == N_PTS - 1) bmE[3] = v;
        }
    }
    __syncthreads();

    // ---- phase 8: WENO for g = i0 + tid (skip global wrap points 0, N-1) ----
    if (tid < POUT) {
        const int g = i0 + tid;
        if (g < N_PTS && g != 0 && g != N_PTS - 1) {
            out[g] = weno_point(u, g, sbm[tid], sbm[tid + 1], sbm[tid + 2]);
        }
    }
}

// ---------------------------------------------------------------------------
// Patch: the two outputs whose bm-neighborhood wraps the array ends
// ---------------------------------------------------------------------------
__global__ __launch_bounds__(64) void patch_kernel(
    const float* __restrict__ u, const float* __restrict__ bmE,
    float* __restrict__ out)
{
    const int t = threadIdx.x;
    if (t == 0)      out[0]         = weno_point(u, 0,         bmE[3], bmE[0], bmE[1]);
    else if (t == 1) out[N_PTS - 1] = weno_point(u, N_PTS - 1, bmE[2], bmE[3], bmE[0]);
}

extern "C" void kernel_launch(void* const* d_in, const int* in_sizes, int n_in,
                              void* d_out, int out_size, void* d_ws, size_t ws_size,
                              hipStream_t stream) {
    const float* u  = (const float*)d_in[0];
    const float* w1 = (const float*)d_in[1];
    const float* b1 = (const float*)d_in[2];
    const float* w2 = (const float*)d_in[3];
    const float* b2 = (const float*)d_in[4];
    const float* w3 = (const float*)d_in[5];
    const float* b3 = (const float*)d_in[6];
    const float* w4 = (const float*)d_in[7];
    const float* b4 = (const float*)d_in[8];
    const float* w5 = (const float*)d_in[9];
    const float* b5 = (const float*)d_in[10];
    const float* w6 = (const float*)d_in[11];
    const float* b6 = (const float*)d_in[12];

    unsigned short* frags = (unsigned short*)d_ws;            // 47104 B
    float* bmE = (float*)((char*)d_ws + BME_OFF);             // 4 f32

    (void)hipFuncSetAttribute((const void*)cnn_weno_kernel,
                              hipFuncAttributeMaxDynamicSharedMemorySize,
                              SMEM_BYTES);

    prep_kernel<<<1, BLK, 0, stream>>>(w2, w3, w4, w5, frags);
    cnn_weno_kernel<<<NBLK, BLK, SMEM_BYTES, stream>>>(u, w1, b1, b2, b3, b4, b5,
                                                       w6, b6, frags, bmE,
                                                       (float*)d_out);
    patch_kernel<<<1, 64, 0, stream>>>(u, bmE, (float*)d_out);
}

// Round 6
// 361.655 us; speedup vs baseline: 8.2889x; 1.0206x over previous
//
#include <hip/hip_runtime.h>
#include <cstdint>

#define N_PTS 2097152          // 2^21
#define MASK  (N_PTS - 1)

constexpr int NPOS = 128;      // grid positions per block (pos q in [0,128))
constexpr int POUT = 112;      // outputs per block: g = i0 + tid, tid < 112
constexpr int BLK  = 256;      // 4 waves
constexpr int NBLK = (N_PTS + POUT - 1) / POUT;   // 18725

// LDS activation strides (u16 units); row stride = odd multiple of 16 B
constexpr int ST1 = 40;    // act1: 20 ch (k-pad to 32), 132 rows (q offset +2)
constexpr int ST2 = 72;    // act2: 40 ch (k-pad to 64), 128 rows
constexpr int ST3 = 104;   // act3: 80 ch (k-pad to 96), 128 rows
constexpr int ST4 = 72;    // act4: 40 ch (k-pad to 64), 130 rows (q offset +1)

constexpr int SLOTA_OFF = 0;
constexpr int SLOTA_SZ  = 128 * ST3 * 2;            // 26624 B (act1 / act3)
constexpr int SLOTB_OFF = SLOTA_SZ;
constexpr int SLOTB_SZ  = 130 * ST4 * 2;            // 18720 B (act2 / act4)
constexpr int TAIL_OFF  = SLOTB_OFF + SLOTB_SZ;     // 45344
// tail f32: sdif 136 | sw1 100 | sb1 20 | sb2 40 | sb3 80 | sb4 40 | sb5 20 | sw6 20 | sb6 1 | sbm 114
constexpr int SMEM_BYTES = TAIL_OFF + 571 * 4 + 4;  // 47632

// precomputed bf16 A-fragments in d_ws (u16 units); frag idx = (t*MT+mt)*KS+ks
constexpr int F2 = 0;          // L2: 5 taps x MT3 x KS1 = 15 frags x 512 u16
constexpr int F3 = 7680;       // L3: 1 x 5 x 2 = 10
constexpr int F4 = 12800;      // L4: 1 x 3 x 3 = 9
constexpr int F5 = 17408;      // L5: 3 x 2 x 2 = 12  -> ends 23552 u16
constexpr int NFRAG2 = 15, NFRAG3 = 10, NFRAG4 = 9, NFRAG5 = 12;
constexpr int BME_OFF = 49152; // 4 edge bm values (f32): bm[0], bm[1], bm[N-2], bm[N-1]

typedef __bf16 bf16x8 __attribute__((ext_vector_type(8)));
typedef unsigned short u16x8 __attribute__((ext_vector_type(8)));
typedef unsigned short u16x4 __attribute__((ext_vector_type(4)));
typedef float f32x4 __attribute__((ext_vector_type(4)));

__device__ __forceinline__ float elu(float x) { return x > 0.f ? x : __expf(x) - 1.f; }

// precise RTNE (weights, done once in prep)
__device__ __forceinline__ unsigned short f2b_rtne(float f) {
    union { float f; unsigned int u; } x; x.f = f;
    return (unsigned short)((x.u + 0x7fffu + ((x.u >> 16) & 1u)) >> 16);
}
// fast round-half-up (activations; <=0.5 ulp, 2 VALU ops)
__device__ __forceinline__ unsigned short f2bf(float f) {
    union { float f; unsigned int u; } x; x.f = f;
    return (unsigned short)((x.u + 0x8000u) >> 16);
}

// ---------------------------------------------------------------------------
// Prep: one fragment per block (46 blocks x 64 lanes). RTNE, zero-padded m/k.
// ---------------------------------------------------------------------------
template<int M, int MT, int CI, int KS, int KT>
__device__ __forceinline__ void pack_one(const float* __restrict__ W,
                                         unsigned short* __restrict__ dst,
                                         int f, int lane)
{
    const int ks = f % KS;
    const int fi = f / KS;
    const int mt = fi % MT;
    const int t  = fi / MT;
    const int m  = mt * 16 + (lane & 15);
    const int kb = ks * 32 + (lane >> 4) * 8;
    u16x8 v;
    #pragma unroll
    for (int j = 0; j < 8; ++j) {
        const int k = kb + j;
        v[j] = f2b_rtne((m < M && k < CI) ? W[(m * CI + k) * KT + t] : 0.f);
    }
    *(u16x8*)(dst + (f * 64 + lane) * 8) = v;
}

__global__ __launch_bounds__(64) void prep_kernel(
    const float* __restrict__ w2, const float* __restrict__ w3,
    const float* __restrict__ w4, const float* __restrict__ w5,
    unsigned short* __restrict__ frags)
{
    const int lane = threadIdx.x;
    const int b = blockIdx.x;
    if (b < NFRAG2)                            pack_one<40, 3, 20, 1, 5>(w2, frags + F2, b, lane);
    else if (b < NFRAG2 + NFRAG3)              pack_one<80, 5, 40, 2, 1>(w3, frags + F3, b - NFRAG2, lane);
    else if (b < NFRAG2 + NFRAG3 + NFRAG4)     pack_one<40, 3, 80, 3, 1>(w4, frags + F4, b - NFRAG2 - NFRAG3, lane);
    else                                       pack_one<20, 2, 40, 2, 3>(w5, frags + F5, b - NFRAG2 - NFRAG3 - NFRAG4, lane);
}

// ---------------------------------------------------------------------------
// Tap-decomposed MFMA layer: out[m, q] = sum_t W_t @ act[:, row q+t].
// ---------------------------------------------------------------------------
template<int TAPS, int MT, int KS, typename Epi>
__device__ __forceinline__ void gemm_tap(const unsigned short* __restrict__ Af,
                                         const unsigned short* __restrict__ Bbuf,
                                         int SB, Epi epi)
{
    const int lane = threadIdx.x & 63;
    const int wv   = threadIdx.x >> 6;
    const int n15  = lane & 15;
    const int quad = lane >> 4;

    #pragma unroll
    for (int nt = 0; nt < 2; ++nt) {
        const int pos = (wv * 2 + nt) * 16 + n15;
        bf16x8 B[TAPS][KS];
        #pragma unroll
        for (int t = 0; t < TAPS; ++t)
            #pragma unroll
            for (int ks = 0; ks < KS; ++ks)
                B[t][ks] = __builtin_bit_cast(bf16x8,
                    *(const u16x8*)(Bbuf + (pos + t) * SB + ks * 32 + quad * 8));
        #pragma unroll
        for (int mt = 0; mt < MT; ++mt) {
            f32x4 acc = {0.f, 0.f, 0.f, 0.f};
            #pragma unroll
            for (int t = 0; t < TAPS; ++t)
                #pragma unroll
                for (int ks = 0; ks < KS; ++ks)
                    acc = __builtin_amdgcn_mfma_f32_16x16x32_bf16(
                        __builtin_bit_cast(bf16x8,
                            *(const u16x8*)(Af + (((t * MT + mt) * KS + ks) * 64 + lane) * 8)),
                        B[t][ks], acc, 0, 0, 0);
            epi(mt, pos, acc);
        }
    }
}

// ---------------------------------------------------------------------------
// WENO5 flux at point i (periodic u), given bm[i-1], bm[i], bm[i+1]
// ---------------------------------------------------------------------------
__device__ __forceinline__ float weno_point(const float* __restrict__ u, int i,
                                            float bmm, float bm0, float bmp)
{
    const float um2 = u[(i - 2) & MASK];
    const float um1 = u[(i - 1) & MASK];
    const float u0  = u[i];
    const float up1 = u[(i + 1) & MASK];
    const float up2 = u[(i + 2) & MASK];
    const float up3 = u[(i + 3) & MASK];

    const float c1312 = 13.f / 12.f;
    const float s6 = 1.f / 6.f;

    const float f0p = (11.f * up1 - 7.f * up2 + 2.f * up3) * s6;
    const float f1p = (2.f * u0 + 5.f * up1 - up2) * s6;
    const float f2p = (-um1 + 5.f * u0 + 2.f * up1) * s6;
    const float f0n = (11.f * u0 - 7.f * up1 + 2.f * up2) * s6;
    const float f1n = (2.f * um1 + 5.f * u0 - up1) * s6;
    const float f2n = (-um2 + 5.f * um1 + 2.f * u0) * s6;

    float t0, t1;
    t0 = up1 - 2.f * up2 + up3;  t1 = 3.f * up1 - 4.f * up2 + up3;
    float bp0 = c1312 * t0 * t0 + 0.25f * t1 * t1;
    t0 = u0 - 2.f * up1 + up2;   t1 = u0 - up2;
    float bp1 = c1312 * t0 * t0 + 0.25f * t1 * t1;
    t0 = um1 - 2.f * u0 + up1;   t1 = um1 - 4.f * u0 + 3.f * up1;
    float bp2 = c1312 * t0 * t0 + 0.25f * t1 * t1;
    t0 = u0 - 2.f * up1 + up2;   t1 = 3.f * u0 - 4.f * up1 + up2;
    float bn0 = c1312 * t0 * t0 + 0.25f * t1 * t1;
    t0 = um1 - 2.f * u0 + up1;   t1 = um1 - up1;
    float bn1 = c1312 * t0 * t0 + 0.25f * t1 * t1;
    t0 = um2 - 2.f * um1 + u0;   t1 = um2 - 4.f * um1 + 3.f * u0;
    float bn2 = c1312 * t0 * t0 + 0.25f * t1 * t1;

    bp0 *= bmp; bp1 *= bm0; bp2 *= bmm;
    bn0 *= bmp; bn1 *= bm0; bn2 *= bmm;

    const float E = 1e-13f;
    float brs, e0, e1, e2, o0, o1, o2, s;

    brs = bp2 - bp0; brs *= brs;
    e0 = E + bp0; e0 *= e0;
    e1 = E + bp1; e1 *= e1;
    e2 = E + bp2; e2 *= e2;
    o0 = 0.1f * (brs + e0) / e0;
    o1 = 0.6f * (brs + e1) / e1;
    o2 = 0.3f * (brs + e2) / e2;
    s = o0 + o1 + o2;
    const float fluxp = (o0 * f0p + o1 * f1p + o2 * f2p) / s;

    brs = bn2 - bn0; brs *= brs;
    e0 = E + bn0; e0 *= e0;
    e1 = E + bn1; e1 *= e1;
    e2 = E + bn2; e2 *= e2;
    o0 = 0.1f * (brs + e0) / e0;
    o1 = 0.6f * (brs + e1) / e1;
    o2 = 0.3f * (brs + e2) / e2;
    s = o0 + o1 + o2;
    const float fluxn = (o0 * f0n + o1 * f1n + o2 * f2n) / s;

    return fluxp - fluxn;
}

// ---------------------------------------------------------------------------
// Fused CNN + WENO
// ---------------------------------------------------------------------------
__global__ __launch_bounds__(BLK, 3) void cnn_weno_kernel(
    const float* __restrict__ u,
    const float* __restrict__ w1, const float* __restrict__ b1,
    const float* __restrict__ b2, const float* __restrict__ b3,
    const float* __restrict__ b4, const float* __restrict__ b5,
    const float* __restrict__ w6, const float* __restrict__ b6,
    const unsigned short* __restrict__ frags,
    float* __restrict__ bmE,
    float* __restrict__ out)
{
    extern __shared__ char smem[];
    unsigned short* act1 = (unsigned short*)(smem + SLOTA_OFF);  // [132][ST1]
    unsigned short* act3 = (unsigned short*)(smem + SLOTA_OFF);  // [128][ST3]
    unsigned short* act2 = (unsigned short*)(smem + SLOTB_OFF);  // [128][ST2]
    unsigned short* act4 = (unsigned short*)(smem + SLOTB_OFF);  // [130][ST4]
    float* sdif = (float*)(smem + TAIL_OFF);   // 136
    float* sw1  = sdif + 136;                  // 100
    float* sb1  = sw1 + 100;                   // 20
    float* sb2  = sb1 + 20;                    // 40
    float* sb3  = sb2 + 40;                    // 80
    float* sb4  = sb3 + 80;                    // 40
    float* sb5  = sb4 + 40;                    // 20
    float* sw6  = sb5 + 20;                    // 20
    float* sb6  = sw6 + 20;                    // 1
    float* sbm  = sb6 + 1;                     // 114  (sbm[j] = bm at g = i0 + j - 1)

    const int tid  = threadIdx.x;
    const int lane = tid & 63;
    const int wv   = tid >> 6;
    const int n15  = lane & 15;
    const int quad = lane >> 4;
    const int i0   = blockIdx.x * POUT;
    const bool edge = (blockIdx.x == 0) || (blockIdx.x >= NBLK - 1);

    // ---- phase 1: zero PAD regions only (first-touch NaN guard), dif, params ----
    {
        const u16x4 z4 = {0, 0, 0, 0};
        const u16x8 z8 = {0, 0, 0, 0, 0, 0, 0, 0};
        // act1 k-pad cols 20..31 (132 rows)
        for (int i = tid; i < 132 * 3; i += BLK) {
            const int r = i / 3, c = 20 + (i - r * 3) * 4;
            *(u16x4*)(act1 + r * ST1 + c) = z4;
        }
        // act2 k-pad cols 40..63 (128 rows)  [same bytes also cover act4 pads rows 0..127]
        for (int i = tid; i < 128 * 3; i += BLK) {
            const int r = i / 3, c = 40 + (i - r * 3) * 8;
            *(u16x8*)(act2 + r * ST2 + c) = z8;
        }
        // act3 k-pad cols 80..95 (128 rows)
        for (int i = tid; i < 128 * 2; i += BLK) {
            const int r = i >> 1, c = 80 + (i & 1) * 8;
            *(u16x8*)(act3 + r * ST3 + c) = z8;
        }
        // act4 halo rows 0 and 129 (full 64 cols) + pad cols of rows 128,129
        for (int i = tid; i < 2 * 8; i += BLK) {
            const int r = (i < 8) ? 0 : 129, c = (i & 7) * 8;
            *(u16x8*)(act4 + r * ST4 + c) = z8;
        }
        for (int i = tid; i < 2 * 3; i += BLK) {
            const int r = 128 + (i / 3), c = 40 + (i % 3) * 8;
            *(u16x8*)(act4 + r * ST4 + c) = z8;
        }
    }
    for (int d = tid; d < 136; d += BLK) {
        const int g = i0 - 12 + d;             // dif logical q = d-4
        float v = 0.f;
        if (g >= 0 && g < N_PTS) {
            if (g == 0)              v = u[1] - u[0];
            else if (g == N_PTS - 1) v = u[N_PTS - 1] - u[N_PTS - 2];
            else                     v = 0.5f * (u[g + 1] - u[g - 1]);
        }
        sdif[d] = v;
    }
    for (int i = tid; i < 100; i += BLK) sw1[i] = w1[i];
    if (tid < 20)  sb1[tid] = b1[tid];
    else if (tid < 60)  sb2[tid - 20]  = b2[tid - 20];
    else if (tid < 140) sb3[tid - 60]  = b3[tid - 60];
    else if (tid < 180) sb4[tid - 140] = b4[tid - 140];
    else if (tid < 200) sb5[tid - 180] = b5[tid - 180];
    else if (tid < 220) sw6[tid - 200] = w6[tid - 200];
    else if (tid == 220) sb6[0] = b6[0];
    __syncthreads();

    // ---- phase 2: L1 (VALU) -> act1[r][c], r = q+2 in [0,132) ----
    for (int task = tid; task < 132 * 5; task += BLK) {
        const int r  = task / 5;
        const int c0 = (task - r * 5) * 4;
        const float d0 = sdif[r], d1 = sdif[r+1], d2 = sdif[r+2],
                    d3 = sdif[r+3], d4 = sdif[r+4];
        u16x4 ov;
        #pragma unroll
        for (int j = 0; j < 4; ++j) {
            const int c = c0 + j;
            float a = sb1[c] + sw1[c*5]*d0 + sw1[c*5+1]*d1 + sw1[c*5+2]*d2
                             + sw1[c*5+3]*d3 + sw1[c*5+4]*d4;
            a = elu(a);
            if (edge) {
                const int g = i0 - 10 + r;
                if ((unsigned)g >= (unsigned)N_PTS) a = 0.f;
            }
            ov[j] = f2bf(a);
        }
        *(u16x4*)(act1 + r * ST1 + c0) = ov;
    }
    __syncthreads();

    // ---- phase 3: L2 (40ch, 5 taps) act1 -> act2 ----
    gemm_tap<5, 3, 1>(frags + F2, act1, ST1,
        [&](int mt, int pos, f32x4 acc) {
            const int ch0 = mt * 16 + quad * 4;
            if (ch0 >= 40) return;
            u16x4 wvv;
            #pragma unroll
            for (int r = 0; r < 4; ++r) {
                float v = elu(acc[r] + sb2[ch0 + r]);
                if (edge) {
                    const int g = i0 - 8 + pos;
                    if ((unsigned)g >= (unsigned)N_PTS) v = 0.f;
                }
                wvv[r] = f2bf(v);
            }
            *(u16x4*)(act2 + pos * ST2 + ch0) = wvv;
        });
    __syncthreads();

    // ---- phase 4: L3 (80ch, k=1) act2 -> act3 ----
    gemm_tap<1, 5, 2>(frags + F3, act2, ST2,
        [&](int mt, int pos, f32x4 acc) {
            const int ch0 = mt * 16 + quad * 4;
            u16x4 wvv;
            #pragma unroll
            for (int r = 0; r < 4; ++r) {
                float v = elu(acc[r] + sb3[ch0 + r]);
                if (edge) {
                    const int g = i0 - 8 + pos;
                    if ((unsigned)g >= (unsigned)N_PTS) v = 0.f;
                }
                wvv[r] = f2bf(v);
            }
            *(u16x4*)(act3 + pos * ST3 + ch0) = wvv;
        });
    __syncthreads();

    // ---- phase 5: L4 (40ch, k=1) act3 -> act4 (row offset +1) ----
    gemm_tap<1, 3, 3>(frags + F4, act3, ST3,
        [&](int mt, int pos, f32x4 acc) {
            const int ch0 = mt * 16 + quad * 4;
            if (ch0 >= 40) return;
            u16x4 wvv;
            #pragma unroll
            for (int r = 0; r < 4; ++r) {
                float v = elu(acc[r] + sb4[ch0 + r]);
                if (edge) {
                    const int g = i0 - 8 + pos;
                    if ((unsigned)g >= (unsigned)N_PTS) v = 0.f;
                }
                wvv[r] = f2bf(v);
            }
            *(u16x4*)(act4 + (pos + 1) * ST4 + ch0) = wvv;
        });
    __syncthreads();

    // ---- phase 6: L5 (20ch, 3 taps) + L6 + sigmoid fused -> sbm ----
    // Channels of pos live in lanes {n15, n15+16, n15+32, n15+48}: cross-quad
    // shuffle-reduce the w6-weighted partials; no act6 round-trip.
    {
        const unsigned short* Af = frags + F5;
        #pragma unroll
        for (int nt = 0; nt < 2; ++nt) {
            const int pos = (wv * 2 + nt) * 16 + n15;
            bf16x8 B[3][2];
            #pragma unroll
            for (int t = 0; t < 3; ++t)
                #pragma unroll
                for (int ks = 0; ks < 2; ++ks)
                    B[t][ks] = __builtin_bit_cast(bf16x8,
                        *(const u16x8*)(act4 + (pos + t) * ST4 + ks * 32 + quad * 8));
            f32x4 a0 = {0.f, 0.f, 0.f, 0.f};
            f32x4 a1 = {0.f, 0.f, 0.f, 0.f};
            #pragma unroll
            for (int t = 0; t < 3; ++t)
                #pragma unroll
                for (int ks = 0; ks < 2; ++ks) {
                    a0 = __builtin_amdgcn_mfma_f32_16x16x32_bf16(
                        __builtin_bit_cast(bf16x8,
                            *(const u16x8*)(Af + (((t * 2 + 0) * 2 + ks) * 64 + lane) * 8)),
                        B[t][ks], a0, 0, 0, 0);
                    a1 = __builtin_amdgcn_mfma_f32_16x16x32_bf16(
                        __builtin_bit_cast(bf16x8,
                            *(const u16x8*)(Af + (((t * 2 + 1) * 2 + ks) * 64 + lane) * 8)),
                        B[t][ks], a1, 0, 0, 0);
                }
            float partial = 0.f;
            const int c0 = quad * 4;
            #pragma unroll
            for (int r = 0; r < 4; ++r) {
                const float v = elu(a0[r] + sb5[c0 + r]);
                partial += sw6[c0 + r] * v;
            }
            if (quad == 0) {
                #pragma unroll
                for (int r = 0; r < 4; ++r) {
                    const float v = elu(a1[r] + sb5[16 + r]);
                    partial += sw6[16 + r] * v;
                }
            }
            partial += __shfl_xor(partial, 16, 64);
            partial += __shfl_xor(partial, 32, 64);
            if (quad == 0) {
                const float bmv = 1.f / (1.f + __expf(-(partial + sb6[0]))) + 0.1f;
                if (pos >= 7 && pos < 121) sbm[pos - 7] = bmv;
                if (blockIdx.x == 0) {
                    if (pos == 8) bmE[0] = bmv;
                    else if (pos == 9) bmE[1] = bmv;
                }
                if (blockIdx.x == NBLK - 1) {
                    if (pos == 70) bmE[2] = bmv;       // g = N-2
                    else if (pos == 71) bmE[3] = bmv;  // g = N-1
                }
            }
        }
    }
    __syncthreads();

    // ---- phase 7: WENO for g = i0 + tid (global wrap points via patch) ----
    if (tid < POUT) {
        const int g = i0 + tid;
        if (g < N_PTS && g != 0 && g != N_PTS - 1) {
            out[g] = weno_point(u, g, sbm[tid], sbm[tid + 1], sbm[tid + 2]);
        }
    }
}

// ---------------------------------------------------------------------------
// Patch: the two outputs whose bm-neighborhood wraps the array ends
// ---------------------------------------------------------------------------
__global__ __launch_bounds__(64) void patch_kernel(
    const float* __restrict__ u, const float* __restrict__ bmE,
    float* __restrict__ out)
{
    const int t = threadIdx.x;
    if (t == 0)      out[0]         = weno_point(u, 0,         bmE[3], bmE[0], bmE[1]);
    else if (t == 1) out[N_PTS - 1] = weno_point(u, N_PTS - 1, bmE[2], bmE[3], bmE[0]);
}

extern "C" void kernel_launch(void* const* d_in, const int* in_sizes, int n_in,
                              void* d_out, int out_size, void* d_ws, size_t ws_size,
                              hipStream_t stream) {
    const float* u  = (const float*)d_in[0];
    const float* w1 = (const float*)d_in[1];
    const float* b1 = (const float*)d_in[2];
    const float* w2 = (const float*)d_in[3];
    const float* b2 = (const float*)d_in[4];
    const float* w3 = (const float*)d_in[5];
    const float* b3 = (const float*)d_in[6];
    const float* w4 = (const float*)d_in[7];
    const float* b4 = (const float*)d_in[8];
    const float* w5 = (const float*)d_in[9];
    const float* b5 = (const float*)d_in[10];
    const float* w6 = (const float*)d_in[11];
    const float* b6 = (const float*)d_in[12];

    unsigned short* frags = (unsigned short*)d_ws;            // 47104 B
    float* bmE = (float*)((char*)d_ws + BME_OFF);             // 4 f32

    (void)hipFuncSetAttribute((const void*)cnn_weno_kernel,
                              hipFuncAttributeMaxDynamicSharedMemorySize,
                              SMEM_BYTES);

    prep_kernel<<<NFRAG2 + NFRAG3 + NFRAG4 + NFRAG5, 64, 0, stream>>>(w2, w3, w4, w5, frags);
    cnn_weno_kernel<<<NBLK, BLK, SMEM_BYTES, stream>>>(u, w1, b1, b2, b3, b4, b5,
                                                       w6, b6, frags, bmE,
                                                       (float*)d_out);
    patch_kernel<<<1, 64, 0, stream>>>(u, bmE, (float*)d_out);
}

// Round 7
// 331.535 us; speedup vs baseline: 9.0419x; 1.0909x over previous
//
#include <hip/hip_runtime.h>
#include <cstdint>

#define N_PTS 2097152          // 2^21
#define MASK  (N_PTS - 1)

constexpr int NPOS = 128;      // grid positions per block (pos q in [0,128))
constexpr int POUT = 116;      // outputs per block: g = i0 + tid, tid < 116
constexpr int GOFF = 6;        // g = i0 - GOFF + q
constexpr int BLK  = 256;      // 4 waves
constexpr int NBLK = (N_PTS + POUT - 1) / POUT;   // 18079

// LDS activation strides (u16 units); row stride = odd multiple of 16 B
constexpr int ST1 = 40;    // act1: 20 ch + bias col 20 (k-pad 32), 132 rows (q off +2)
constexpr int ST2 = 72;    // act2: 40 ch + bias col 40 (k-pad 64), 128 rows
constexpr int ST3 = 104;   // act3: 80 ch + bias col 80 (k-pad 96), 128 rows
constexpr int ST4 = 72;    // act4: 40 ch + bias col 40 (k-pad 64), 130 rows (q off +1)

constexpr int SLOTA_OFF = 0;
constexpr int SLOTA_SZ  = 128 * ST3 * 2;            // 26624 B (act1 / act3)
constexpr int SLOTB_OFF = SLOTA_SZ;
constexpr int SLOTB_SZ  = 130 * ST4 * 2;            // 18720 B (act2 / act4)
constexpr int TAIL_OFF  = SLOTB_OFF + SLOTB_SZ;     // 45344
// tail f32: sdif 136 | sw1 100 | sb1 20 | sw6 20 | sb6 1 | sbm 118  = 395
constexpr int SMEM_BYTES = TAIL_OFF + 395 * 4;      // 46924

// precomputed bf16 A-fragments in d_ws (u16 units); frag idx = (t*MT+mt)*KS+ks
constexpr int F2 = 0;          // L2: 5 taps x MT3 x KS1 = 15 frags x 512 u16
constexpr int F3 = 7680;       // L3: 1 x 5 x 2 = 10
constexpr int F4 = 12800;      // L4: 1 x 3 x 3 = 9
constexpr int F5 = 17408;      // L5: 3 x 2 x 2 = 12  -> ends 23552 u16
constexpr int NFRAG2 = 15, NFRAG3 = 10, NFRAG4 = 9, NFRAG5 = 12;
constexpr int BME_OFF = 49152; // 4 edge bm values (f32): bm[0], bm[1], bm[N-2], bm[N-1]

typedef __bf16 bf16x8 __attribute__((ext_vector_type(8)));
typedef unsigned short u16x8 __attribute__((ext_vector_type(8)));
typedef unsigned short u16x4 __attribute__((ext_vector_type(4)));
typedef float f32x4 __attribute__((ext_vector_type(4)));

constexpr unsigned short BF16_ONE = 0x3F80;

__device__ __forceinline__ float elu(float x) { return x > 0.f ? x : __expf(x) - 1.f; }

// precise RTNE (weights, done once in prep)
__device__ __forceinline__ unsigned short f2b_rtne(float f) {
    union { float f; unsigned int u; } x; x.f = f;
    return (unsigned short)((x.u + 0x7fffu + ((x.u >> 16) & 1u)) >> 16);
}
// fast round-half-up (activations; <=0.5 ulp, 2 VALU ops)
__device__ __forceinline__ unsigned short f2bf(float f) {
    union { float f; unsigned int u; } x; x.f = f;
    return (unsigned short)((x.u + 0x8000u) >> 16);
}

// ---------------------------------------------------------------------------
// Prep: one fragment per block (46 x 64 lanes). RTNE, zero-padded m/k.
// Bias folded at k == CI on tap biasTap (activation bias column holds 1.0).
// ---------------------------------------------------------------------------
template<int M, int MT, int CI, int KS, int KT>
__device__ __forceinline__ void pack_one(const float* __restrict__ W,
                                         const float* __restrict__ Bias, int biasTap,
                                         unsigned short* __restrict__ dst,
                                         int f, int lane)
{
    const int ks = f % KS;
    const int fi = f / KS;
    const int mt = fi % MT;
    const int t  = fi / MT;
    const int m  = mt * 16 + (lane & 15);
    const int kb = ks * 32 + (lane >> 4) * 8;
    u16x8 v;
    #pragma unroll
    for (int j = 0; j < 8; ++j) {
        const int k = kb + j;
        float val = 0.f;
        if (m < M) {
            if (k < CI)                          val = W[(m * CI + k) * KT + t];
            else if (k == CI && t == biasTap)    val = Bias[m];
        }
        v[j] = f2b_rtne(val);
    }
    *(u16x8*)(dst + (f * 64 + lane) * 8) = v;
}

__global__ __launch_bounds__(64) void prep_kernel(
    const float* __restrict__ w2, const float* __restrict__ b2,
    const float* __restrict__ w3, const float* __restrict__ b3,
    const float* __restrict__ w4, const float* __restrict__ b4,
    const float* __restrict__ w5, const float* __restrict__ b5,
    unsigned short* __restrict__ frags)
{
    const int lane = threadIdx.x;
    const int b = blockIdx.x;
    if (b < NFRAG2)
        pack_one<40, 3, 20, 1, 5>(w2, b2, 2, frags + F2, b, lane);
    else if (b < NFRAG2 + NFRAG3)
        pack_one<80, 5, 40, 2, 1>(w3, b3, 0, frags + F3, b - NFRAG2, lane);
    else if (b < NFRAG2 + NFRAG3 + NFRAG4)
        pack_one<40, 3, 80, 3, 1>(w4, b4, 0, frags + F4, b - NFRAG2 - NFRAG3, lane);
    else
        pack_one<20, 2, 40, 2, 3>(w5, b5, 1, frags + F5, b - NFRAG2 - NFRAG3 - NFRAG4, lane);
}

// ---------------------------------------------------------------------------
// Tap-decomposed MFMA layer with A-fragments PRELOADED to registers.
// out[m, q] = sum_t W_t @ act[:, row q+t]  (+bias via 1.0-column).
// ---------------------------------------------------------------------------
template<int TAPS, int MT, int KS, typename Epi>
__device__ __forceinline__ void gemm_tap(const unsigned short* __restrict__ Af,
                                         const unsigned short* __restrict__ Bbuf,
                                         int SB, Epi epi)
{
    const int lane = threadIdx.x & 63;
    const int wv   = threadIdx.x >> 6;
    const int n15  = lane & 15;

    bf16x8 A[TAPS * MT * KS];
    #pragma unroll
    for (int f = 0; f < TAPS * MT * KS; ++f)
        A[f] = __builtin_bit_cast(bf16x8, *(const u16x8*)(Af + (f * 64 + lane) * 8));

    const int quad = lane >> 4;
    #pragma unroll
    for (int nt = 0; nt < 2; ++nt) {
        const int pos = (wv * 2 + nt) * 16 + n15;
        bf16x8 B[TAPS][KS];
        #pragma unroll
        for (int t = 0; t < TAPS; ++t)
            #pragma unroll
            for (int ks = 0; ks < KS; ++ks)
                B[t][ks] = __builtin_bit_cast(bf16x8,
                    *(const u16x8*)(Bbuf + (pos + t) * SB + ks * 32 + quad * 8));
        #pragma unroll
        for (int mt = 0; mt < MT; ++mt) {
            f32x4 acc = {0.f, 0.f, 0.f, 0.f};
            #pragma unroll
            for (int t = 0; t < TAPS; ++t)
                #pragma unroll
                for (int ks = 0; ks < KS; ++ks)
                    acc = __builtin_amdgcn_mfma_f32_16x16x32_bf16(
                        A[(t * MT + mt) * KS + ks], B[t][ks], acc, 0, 0, 0);
            epi(mt, pos, acc);
        }
    }
}

// ---------------------------------------------------------------------------
// WENO5 flux at point i (periodic u), given bm[i-1], bm[i], bm[i+1]
// ---------------------------------------------------------------------------
__device__ __forceinline__ float weno_point(const float* __restrict__ u, int i,
                                            float bmm, float bm0, float bmp)
{
    const float um2 = u[(i - 2) & MASK];
    const float um1 = u[(i - 1) & MASK];
    const float u0  = u[i];
    const float up1 = u[(i + 1) & MASK];
    const float up2 = u[(i + 2) & MASK];
    const float up3 = u[(i + 3) & MASK];

    const float c1312 = 13.f / 12.f;
    const float s6 = 1.f / 6.f;

    const float f0p = (11.f * up1 - 7.f * up2 + 2.f * up3) * s6;
    const float f1p = (2.f * u0 + 5.f * up1 - up2) * s6;
    const float f2p = (-um1 + 5.f * u0 + 2.f * up1) * s6;
    const float f0n = (11.f * u0 - 7.f * up1 + 2.f * up2) * s6;
    const float f1n = (2.f * um1 + 5.f * u0 - up1) * s6;
    const float f2n = (-um2 + 5.f * um1 + 2.f * u0) * s6;

    float t0, t1;
    t0 = up1 - 2.f * up2 + up3;  t1 = 3.f * up1 - 4.f * up2 + up3;
    float bp0 = c1312 * t0 * t0 + 0.25f * t1 * t1;
    t0 = u0 - 2.f * up1 + up2;   t1 = u0 - up2;
    float bp1 = c1312 * t0 * t0 + 0.25f * t1 * t1;
    t0 = um1 - 2.f * u0 + up1;   t1 = um1 - 4.f * u0 + 3.f * up1;
    float bp2 = c1312 * t0 * t0 + 0.25f * t1 * t1;
    t0 = u0 - 2.f * up1 + up2;   t1 = 3.f * u0 - 4.f * up1 + up2;
    float bn0 = c1312 * t0 * t0 + 0.25f * t1 * t1;
    t0 = um1 - 2.f * u0 + up1;   t1 = um1 - up1;
    float bn1 = c1312 * t0 * t0 + 0.25f * t1 * t1;
    t0 = um2 - 2.f * um1 + u0;   t1 = um2 - 4.f * um1 + 3.f * u0;
    float bn2 = c1312 * t0 * t0 + 0.25f * t1 * t1;

    bp0 *= bmp; bp1 *= bm0; bp2 *= bmm;
    bn0 *= bmp; bn1 *= bm0; bn2 *= bmm;

    const float E = 1e-13f;
    float brs, e0, e1, e2, o0, o1, o2, s;

    brs = bp2 - bp0; brs *= brs;
    e0 = E + bp0; e0 *= e0;
    e1 = E + bp1; e1 *= e1;
    e2 = E + bp2; e2 *= e2;
    o0 = 0.1f * (brs + e0) / e0;
    o1 = 0.6f * (brs + e1) / e1;
    o2 = 0.3f * (brs + e2) / e2;
    s = o0 + o1 + o2;
    const float fluxp = (o0 * f0p + o1 * f1p + o2 * f2p) / s;

    brs = bn2 - bn0; brs *= brs;
    e0 = E + bn0; e0 *= e0;
    e1 = E + bn1; e1 *= e1;
    e2 = E + bn2; e2 *= e2;
    o0 = 0.1f * (brs + e0) / e0;
    o1 = 0.6f * (brs + e1) / e1;
    o2 = 0.3f * (brs + e2) / e2;
    s = o0 + o1 + o2;
    const float fluxn = (o0 * f0n + o1 * f1n + o2 * f2n) / s;

    return fluxp - fluxn;
}

// ---------------------------------------------------------------------------
// Fused CNN + WENO
// ---------------------------------------------------------------------------
__global__ __launch_bounds__(BLK, 3) void cnn_weno_kernel(
    const float* __restrict__ u,
    const float* __restrict__ w1, const float* __restrict__ b1,
    const float* __restrict__ w6, const float* __restrict__ b6,
    const unsigned short* __restrict__ frags,
    float* __restrict__ bmE,
    float* __restrict__ out)
{
    extern __shared__ char smem[];
    unsigned short* act1 = (unsigned short*)(smem + SLOTA_OFF);  // [132][ST1]
    unsigned short* act3 = (unsigned short*)(smem + SLOTA_OFF);  // [128][ST3]
    unsigned short* act2 = (unsigned short*)(smem + SLOTB_OFF);  // [128][ST2]
    unsigned short* act4 = (unsigned short*)(smem + SLOTB_OFF);  // [130][ST4]
    float* sdif = (float*)(smem + TAIL_OFF);   // 136
    float* sw1  = sdif + 136;                  // 100
    float* sb1  = sw1 + 100;                   // 20
    float* sw6  = sb1 + 20;                    // 20
    float* sb6  = sw6 + 20;                    // 1
    float* sbm  = sb6 + 1;                     // 118  (sbm[j] = bm at q = j + 5)

    const int tid  = threadIdx.x;
    const int lane = tid & 63;
    const int wv   = tid >> 6;
    const int n15  = lane & 15;
    const int quad = lane >> 4;
    const int i0   = blockIdx.x * POUT;
    const bool edge = (blockIdx.x == 0) || (blockIdx.x >= NBLK - 1);

    // ---- phase 1: pad columns (bias col = 1.0, rest 0), dif, params ----
    {
        // act1 rows 0..131, cols 20..31; col 20 = 1.0
        for (int i = tid; i < 132 * 3; i += BLK) {
            const int r = i / 3, j = i - r * 3;
            u16x4 v = {0, 0, 0, 0};
            if (j == 0) v[0] = BF16_ONE;
            *(u16x4*)(act1 + r * ST1 + 20 + j * 4) = v;
        }
        // SLOTB (act2/act4 shared) rows 0..129, cols 40..63; col 40 = 1.0
        for (int i = tid; i < 130 * 3; i += BLK) {
            const int r = i / 3, j = i - r * 3;
            u16x8 v = {0, 0, 0, 0, 0, 0, 0, 0};
            if (j == 0) v[0] = BF16_ONE;
            *(u16x8*)(act2 + r * ST2 + 40 + j * 8) = v;
        }
        // act3 rows 0..127, cols 80..95; col 80 = 1.0
        for (int i = tid; i < 128 * 2; i += BLK) {
            const int r = i >> 1, j = i & 1;
            u16x8 v = {0, 0, 0, 0, 0, 0, 0, 0};
            if (j == 0) v[0] = BF16_ONE;
            *(u16x8*)(act3 + r * ST3 + 80 + j * 8) = v;
        }
        // act4 row 129 data cols (never overwritten; NaN guard — its only
        // consumer is bm at pos 127, which is outside the sbm range)
        if (tid < 5) {
            const u16x8 z8 = {0, 0, 0, 0, 0, 0, 0, 0};
            *(u16x8*)(act4 + 129 * ST4 + tid * 8) = z8;
        }
    }
    for (int d = tid; d < 136; d += BLK) {
        const int g = i0 - 10 + d;             // dif logical q = d - 4
        float v = 0.f;
        if (g >= 0 && g < N_PTS) {
            if (g == 0)              v = u[1] - u[0];
            else if (g == N_PTS - 1) v = u[N_PTS - 1] - u[N_PTS - 2];
            else                     v = 0.5f * (u[g + 1] - u[g - 1]);
        }
        sdif[d] = v;
    }
    for (int i = tid; i < 100; i += BLK) sw1[i] = w1[i];
    if (tid < 20)       sb1[tid] = b1[tid];
    else if (tid < 40)  sw6[tid - 20] = w6[tid - 20];
    else if (tid == 40) sb6[0] = b6[0];
    __syncthreads();

    // ---- phase 2: L1 (VALU) -> act1[r][c], r = q'+2 in [0,132) ----
    for (int task = tid; task < 132 * 5; task += BLK) {
        const int r  = task / 5;
        const int c0 = (task - r * 5) * 4;
        const float d0 = sdif[r], d1 = sdif[r+1], d2 = sdif[r+2],
                    d3 = sdif[r+3], d4 = sdif[r+4];
        u16x4 ov;
        #pragma unroll
        for (int j = 0; j < 4; ++j) {
            const int c = c0 + j;
            float a = sb1[c] + sw1[c*5]*d0 + sw1[c*5+1]*d1 + sw1[c*5+2]*d2
                             + sw1[c*5+3]*d3 + sw1[c*5+4]*d4;
            a = elu(a);
            if (edge) {
                const int g = i0 + r - 8;      // g = i0 - 6 + (r - 2)
                if ((unsigned)g >= (unsigned)N_PTS) a = 0.f;
            }
            ov[j] = f2bf(a);
        }
        *(u16x4*)(act1 + r * ST1 + c0) = ov;
    }
    __syncthreads();

    // ---- phase 3: L2 (40ch, 5 taps, bias folded) act1 -> act2 ----
    gemm_tap<5, 3, 1>(frags + F2, act1, ST1,
        [&](int mt, int pos, f32x4 acc) {
            const int ch0 = mt * 16 + quad * 4;
            if (ch0 >= 40) return;
            u16x4 wvv;
            #pragma unroll
            for (int r = 0; r < 4; ++r) {
                float v = elu(acc[r]);
                if (edge) {
                    const int g = i0 - GOFF + pos;
                    if ((unsigned)g >= (unsigned)N_PTS) v = 0.f;
                }
                wvv[r] = f2bf(v);
            }
            *(u16x4*)(act2 + pos * ST2 + ch0) = wvv;
        });
    __syncthreads();

    // ---- phase 4: L3 (80ch, k=1, bias folded) act2 -> act3 ----
    gemm_tap<1, 5, 2>(frags + F3, act2, ST2,
        [&](int mt, int pos, f32x4 acc) {
            const int ch0 = mt * 16 + quad * 4;
            u16x4 wvv;
            #pragma unroll
            for (int r = 0; r < 4; ++r) {
                float v = elu(acc[r]);
                if (edge) {
                    const int g = i0 - GOFF + pos;
                    if ((unsigned)g >= (unsigned)N_PTS) v = 0.f;
                }
                wvv[r] = f2bf(v);
            }
            *(u16x4*)(act3 + pos * ST3 + ch0) = wvv;
        });
    __syncthreads();

    // ---- phase 5: L4 (40ch, k=1, bias folded) act3 -> act4 (row off +1) ----
    gemm_tap<1, 3, 3>(frags + F4, act3, ST3,
        [&](int mt, int pos, f32x4 acc) {
            const int ch0 = mt * 16 + quad * 4;
            if (ch0 >= 40) return;
            u16x4 wvv;
            #pragma unroll
            for (int r = 0; r < 4; ++r) {
                float v = elu(acc[r]);
                if (edge) {
                    const int g = i0 - GOFF + pos;
                    if ((unsigned)g >= (unsigned)N_PTS) v = 0.f;
                }
                wvv[r] = f2bf(v);
            }
            *(u16x4*)(act4 + (pos + 1) * ST4 + ch0) = wvv;
        });
    __syncthreads();

    // ---- phase 6: L5 (20ch, 3 taps, bias folded) + L6 + sigmoid -> sbm ----
    {
        const unsigned short* Af = frags + F5;
        bf16x8 A5[12];
        #pragma unroll
        for (int f = 0; f < 12; ++f)
            A5[f] = __builtin_bit_cast(bf16x8, *(const u16x8*)(Af + (f * 64 + lane) * 8));

        #pragma unroll
        for (int nt = 0; nt < 2; ++nt) {
            const int pos = (wv * 2 + nt) * 16 + n15;
            bf16x8 B[3][2];
            #pragma unroll
            for (int t = 0; t < 3; ++t)
                #pragma unroll
                for (int ks = 0; ks < 2; ++ks)
                    B[t][ks] = __builtin_bit_cast(bf16x8,
                        *(const u16x8*)(act4 + (pos + t) * ST4 + ks * 32 + quad * 8));
            f32x4 a0 = {0.f, 0.f, 0.f, 0.f};
            f32x4 a1 = {0.f, 0.f, 0.f, 0.f};
            #pragma unroll
            for (int t = 0; t < 3; ++t)
                #pragma unroll
                for (int ks = 0; ks < 2; ++ks) {
                    a0 = __builtin_amdgcn_mfma_f32_16x16x32_bf16(
                        A5[(t * 2 + 0) * 2 + ks], B[t][ks], a0, 0, 0, 0);
                    a1 = __builtin_amdgcn_mfma_f32_16x16x32_bf16(
                        A5[(t * 2 + 1) * 2 + ks], B[t][ks], a1, 0, 0, 0);
                }
            float partial = 0.f;
            const int c0 = quad * 4;
            #pragma unroll
            for (int r = 0; r < 4; ++r)
                partial += sw6[c0 + r] * elu(a0[r]);
            if (quad == 0) {
                #pragma unroll
                for (int r = 0; r < 4; ++r)
                    partial += sw6[16 + r] * elu(a1[r]);
            }
            partial += __shfl_xor(partial, 16, 64);
            partial += __shfl_xor(partial, 32, 64);
            if (quad == 0) {
                const float bmv = 1.f / (1.f + __expf(-(partial + sb6[0]))) + 0.1f;
                if (pos >= 5 && pos < 123) sbm[pos - 5] = bmv;
                if (edge) {
                    const int g = i0 - GOFF + pos;
                    if (blockIdx.x == 0) {
                        if (g == 0) bmE[0] = bmv;
                        else if (g == 1) bmE[1] = bmv;
                    }
                    if (blockIdx.x == NBLK - 1) {
                        if (g == N_PTS - 2) bmE[2] = bmv;
                        else if (g == N_PTS - 1) bmE[3] = bmv;
                    }
                }
            }
        }
    }
    __syncthreads();

    // ---- phase 7: WENO for g = i0 + tid (global wrap points via patch) ----
    if (tid < POUT) {
        const int g = i0 + tid;
        if (g < N_PTS && g != 0 && g != N_PTS - 1) {
            out[g] = weno_point(u, g, sbm[tid], sbm[tid + 1], sbm[tid + 2]);
        }
    }
}

// ---------------------------------------------------------------------------
// Patch: the two outputs whose bm-neighborhood wraps the array ends
// ---------------------------------------------------------------------------
__global__ __launch_bounds__(64) void patch_kernel(
    const float* __restrict__ u, const float* __restrict__ bmE,
    float* __restrict__ out)
{
    const int t = threadIdx.x;
    if (t == 0)      out[0]         = weno_point(u, 0,         bmE[3], bmE[0], bmE[1]);
    else if (t == 1) out[N_PTS - 1] = weno_point(u, N_PTS - 1, bmE[2], bmE[3], bmE[0]);
}

extern "C" void kernel_launch(void* const* d_in, const int* in_sizes, int n_in,
                              void* d_out, int out_size, void* d_ws, size_t ws_size,
                              hipStream_t stream) {
    const float* u  = (const float*)d_in[0];
    const float* w1 = (const float*)d_in[1];
    const float* b1 = (const float*)d_in[2];
    const float* w2 = (const float*)d_in[3];
    const float* b2 = (const float*)d_in[4];
    const float* w3 = (const float*)d_in[5];
    const float* b3 = (const float*)d_in[6];
    const float* w4 = (const float*)d_in[7];
    const float* b4 = (const float*)d_in[8];
    const float* w5 = (const float*)d_in[9];
    const float* b5 = (const float*)d_in[10];
    const float* w6 = (const float*)d_in[11];
    const float* b6 = (const float*)d_in[12];

    unsigned short* frags = (unsigned short*)d_ws;            // 47104 B
    float* bmE = (float*)((char*)d_ws + BME_OFF);             // 4 f32

    (void)hipFuncSetAttribute((const void*)cnn_weno_kernel,
                              hipFuncAttributeMaxDynamicSharedMemorySize,
                              SMEM_BYTES);

    prep_kernel<<<NFRAG2 + NFRAG3 + NFRAG4 + NFRAG5, 64, 0, stream>>>(
        w2, b2, w3, b3, w4, b4, w5, b5, frags);
    cnn_weno_kernel<<<NBLK, BLK, SMEM_BYTES, stream>>>(u, w1, b1, w6, b6,
                                                       frags, bmE, (float*)d_out);
    patch_kernel<<<1, 64, 0, stream>>>(u, bmE, (float*)d_out);
}